// Round 1
// baseline (249.817 us; speedup 1.0000x reference)
//
#include <hip/hip_runtime.h>
#include <hip/hip_bf16.h>
#include <math.h>

typedef __hip_bfloat16 bf16;
typedef __attribute__((ext_vector_type(8))) short short8;
typedef __attribute__((ext_vector_type(4))) short short4v;
typedef __attribute__((ext_vector_type(4))) float f32x4;

#define NSEQ 2304
#define CDIM 256
#define NHD  4
#define DH   64

#if __has_builtin(__builtin_amdgcn_exp2f)
#define EXP2F __builtin_amdgcn_exp2f
#else
#define EXP2F exp2f
#endif

static __device__ __forceinline__ f32x4 mfma_bf16(short8 a, short8 b, f32x4 c) {
  return __builtin_amdgcn_mfma_f32_16x16x32_bf16(a, b, c, 0, 0, 0);
}
static __device__ __forceinline__ short8 ld8(const bf16* p) {
  return *reinterpret_cast<const short8*>(p);
}
static __device__ __forceinline__ short8 lds8(const bf16* p) {
  return *reinterpret_cast<const short8*>(p);
}
static __device__ __forceinline__ float b2f(short v) {
  unsigned int u = ((unsigned int)(unsigned short)v) << 16;
  return __uint_as_float(u);
}
static __device__ __forceinline__ short f2b(float f) {
  bf16 h = __float2bfloat16(f);
  return *reinterpret_cast<short*>(&h);
}

// ---------------- dtype probe ----------------
__global__ __launch_bounds__(256) void detect_kernel(const void* __restrict__ xraw,
                                                     int* __restrict__ flag) {
  int t = threadIdx.x;
  const unsigned short* s = (const unsigned short*)xraw;
  int bad = 0;
#pragma unroll
  for (int i = 0; i < 8; ++i) {
    unsigned idx = (((unsigned)(t * 8 + i)) * 9173u) & ((1u << 20) - 1);
    unsigned short v = s[idx * 2];
    unsigned e = (v >> 7) & 0xFFu;
    if (e > 133u) bad++;
  }
  __shared__ int tot;
  if (t == 0) tot = 0;
  __syncthreads();
  atomicAdd(&tot, bad);
  __syncthreads();
  if (t == 0) flag[0] = (tot >= 16) ? 1 : 0;
}

// ---------------- fused conversion of all float inputs ----------------
__global__ __launch_bounds__(256) void cvt_all_kernel(const void* sx, const void* sqkv, const void* sproj,
                                                      const void* sw1, const void* sw2,
                                                      const void* g1, const void* b1, const void* g2,
                                                      const void* b2, const void* bias1, const void* bias2,
                                                      bf16* dx, bf16* dqkv, bf16* dproj,
                                                      bf16* dw1, bf16* dw2, bf16* dsm,
                                                      const int* __restrict__ flag) {
  int is32 = flag[0];
  int bid = blockIdx.x;
  const void* src; bf16* dst; int i4;
  if (bid < 2304)      { src = sx;    dst = dx;    i4 = bid * 256 + threadIdx.x; }
  else if (bid < 2496) { src = sqkv;  dst = dqkv;  i4 = (bid - 2304) * 256 + threadIdx.x; }
  else if (bid < 2560) { src = sproj; dst = dproj; i4 = (bid - 2496) * 256 + threadIdx.x; }
  else if (bid < 2816) { src = sw1;   dst = dw1;   i4 = (bid - 2560) * 256 + threadIdx.x; }
  else if (bid < 3072) { src = sw2;   dst = dw2;   i4 = (bid - 2816) * 256 + threadIdx.x; }
  else {
    const void* srcs[6] = {g1, b1, g2, b2, bias1, bias2};
    const int ns[6] = {256, 256, 256, 256, 1024, 256};
    const int off[6] = {0, 256, 512, 768, 1024, 2048};
    int t = threadIdx.x;
#pragma unroll
    for (int j = 0; j < 6; ++j)
      for (int i = t; i < ns[j]; i += 256) {
        if (is32) dsm[off[j] + i] = __float2bfloat16(((const float*)srcs[j])[i]);
        else      dsm[off[j] + i] = ((const bf16*)srcs[j])[i];
      }
    return;
  }
  if (is32) {
    float4 v = ((const float4*)src)[i4];
    short4v o;
    o[0] = f2b(v.x); o[1] = f2b(v.y); o[2] = f2b(v.z); o[3] = f2b(v.w);
    ((short4v*)dst)[i4] = o;
  } else {
    ((short4v*)dst)[i4] = ((const short4v*)src)[i4];
  }
}

// ---------------- QKV GEMM with FUSED RoPE epilogue (r13-validated) ----------------
__global__ __launch_bounds__(256, 1) void qkv_kernel(const bf16* __restrict__ X,
                                                     const bf16* __restrict__ Wqkv,
                                                     bf16* __restrict__ Q, bf16* __restrict__ K,
                                                     bf16* __restrict__ Vt,
                                                     const int* __restrict__ Wp) {
  int wave = threadIdx.x >> 6, lane = threadIdx.x & 63;
  int l15 = lane & 15, quad = lane >> 4;
  int m0 = (blockIdx.x * 4 + wave) * 64;
  int n0 = blockIdx.y * 64;
  const bf16* arow = X + (size_t)(m0 + l15) * CDIM + quad * 8;
  const bf16* brow = Wqkv + (size_t)(n0 + l15) * CDIM + quad * 8;
  f32x4 z = {0.f, 0.f, 0.f, 0.f};
  f32x4 acc[4][4];
#pragma unroll
  for (int j = 0; j < 4; ++j)
#pragma unroll
    for (int i = 0; i < 4; ++i) acc[j][i] = z;

  short8 a[4], b[4];
#pragma unroll
  for (int i = 0; i < 4; ++i) a[i] = ld8(arow + (size_t)i * 16 * CDIM);
#pragma unroll
  for (int j = 0; j < 4; ++j) b[j] = ld8(brow + (size_t)j * 16 * CDIM);
#pragma unroll
  for (int kk = 32; kk <= CDIM; kk += 32) {
    short8 an[4], bn[4];
    if (kk < CDIM) {
#pragma unroll
      for (int i = 0; i < 4; ++i) an[i] = ld8(arow + (size_t)i * 16 * CDIM + kk);
#pragma unroll
      for (int j = 0; j < 4; ++j) bn[j] = ld8(brow + (size_t)j * 16 * CDIM + kk);
    }
#pragma unroll
    for (int j = 0; j < 4; ++j)
#pragma unroll
      for (int i = 0; i < 4; ++i) acc[j][i] = mfma_bf16(b[j], a[i], acc[j][i]);
    if (kk < CDIM) {
#pragma unroll
      for (int i = 0; i < 4; ++i) a[i] = an[i];
#pragma unroll
      for (int j = 0; j < 4; ++j) b[j] = bn[j];
    }
  }

  int which = n0 >> 8, h = (n0 & 255) >> 6;
  if (which == 2) {
#pragma unroll
    for (int j = 0; j < 4; ++j) {
      int d0 = j * 16 + quad * 4;
#pragma unroll
      for (int i = 0; i < 4; ++i) {
        int gm = m0 + i * 16 + l15;
        int bb = gm / NSEQ, n = gm % NSEQ;
        int bh = bb * NHD + h;
#pragma unroll
        for (int r = 0; r < 4; ++r)
          Vt[((size_t)bh * DH + d0 + r) * NSEQ + n] = __float2bfloat16(acc[j][i][r]);
      }
    }
  } else {
    int Wv = Wp[0];
    if (Wv <= 0 || Wv > 65536) Wv = 48;
    bf16* dst = (which == 0) ? Q : K;
    const float cc = -0.28782313662425574f;  // -ln(10000)/32
    const float EC1 = 0.7498942434f, EC2 = 0.5623413252f, EC3 = 0.4216965034f;
#pragma unroll
    for (int i = 0; i < 4; ++i) {
      int gm = m0 + i * 16 + l15;
      int bb = gm / NSEQ, n = gm % NSEQ;
      int bh = bb * NHD + h;
      int py = n / Wv, px = n - py * Wv;
#pragma unroll
      for (int j = 0; j < 4; ++j) {
        int d0 = j * 16 + quad * 4;
        float pos = (d0 & 32) ? (float)px : (float)py;
        int base = d0 & 31;
        float fb = __expf(cc * (float)base);
        float f0 = fb, f1 = fb * EC1, f2 = fb * EC2, f3 = fb * EC3;
        float s0, c0, s1, c1, s2, c2, s3, c3;
        __sincosf(pos * f0, &s0, &c0);
        __sincosf(pos * f1, &s1, &c1);
        __sincosf(pos * f2, &s2, &c2);
        __sincosf(pos * f3, &s3, &c3);
        float a0 = acc[j][i][0], a1 = acc[j][i][1], a2 = acc[j][i][2], a3 = acc[j][i][3];
        short4v ov;
        ov[0] = f2b(a0 * c0 - a1 * s0);
        ov[1] = f2b(a1 * c1 + a0 * s1);
        ov[2] = f2b(a2 * c2 - a3 * s2);
        ov[3] = f2b(a3 * c3 + a2 * s3);
        *reinterpret_cast<short4v*>(dst + ((size_t)bh * NSEQ + n) * DH + d0) = ov;
      }
    }
  }
}

// ---------------- Flash attention ----------------
// V read DIRECTLY from global (Vt is [d][n], fragments are contiguous 16B
// slices of 64B lines; tile is L1/L2-resident) -> V staging + V LDS reads
// removed from the LDS pipe. K stays LDS double-buffered. 192-thread /
// 3-wave / 48-q-row blocks -> grid 16x48 = 768 = exactly 3 blocks/CU
// (removes the 576-on-256 1.33x imbalance tail).
__global__ __launch_bounds__(192, 3) void attn_kernel(const bf16* __restrict__ Q, const bf16* __restrict__ K,
                                                      const bf16* __restrict__ Vt, bf16* __restrict__ AO) {
  int bh = blockIdx.x, qt = blockIdx.y;
  int tid = threadIdx.x;
  int wave = tid >> 6, lane = tid & 63;
  int l15 = lane & 15, quad = lane >> 4;
  int m0 = qt * 48 + wave * 16;
  const bf16* Qb = Q + (size_t)bh * NSEQ * DH;
  const bf16* Kb = K + (size_t)bh * NSEQ * DH;
  const bf16* Vb = Vt + (size_t)bh * DH * NSEQ;

  __shared__ __align__(16) bf16 kbuf[2][64 * 72];
  __shared__ __align__(16) bf16 plds[3][16 * 72];

  // K staging map: 64x64 tile = 512 short8 slots over 192 threads (2-3 each)
  int sa = tid, sb = tid + 192, sc = tid + 384;
  int ra = sa >> 3, ca = (sa & 7) * 8;
  int rb = sb >> 3, cb = (sb & 7) * 8;
  int rc = sc >> 3, cc2 = (sc & 7) * 8;
  bool third = (tid < 128);  // wave-uniform: waves 0,1 do 3 slots, wave 2 does 2

  // Q pre-scaled by 0.125 * log2(e) so p = exp2(s) directly
  const float QS = 0.18033688011112042f;
  short8 bq0 = ld8(Qb + (size_t)(m0 + l15) * DH + quad * 8);
  short8 bq1 = ld8(Qb + (size_t)(m0 + l15) * DH + 32 + quad * 8);
#pragma unroll
  for (int i = 0; i < 8; ++i) {
    bq0[i] = f2b(b2f(bq0[i]) * QS);
    bq1[i] = f2b(b2f(bq1[i]) * QS);
  }

  f32x4 z = {0.f, 0.f, 0.f, 0.f};
  f32x4 o[4] = {z, z, z, z};
  float l_run = 0.f;
  bf16* pb = plds[wave];
  const bf16* vrow = Vb + (size_t)l15 * NSEQ + quad * 8;

  // stage K tile 0
  *reinterpret_cast<short8*>(kbuf[0] + ra * 72 + ca) = ld8(Kb + (size_t)ra * DH + ca);
  *reinterpret_cast<short8*>(kbuf[0] + rb * 72 + cb) = ld8(Kb + (size_t)rb * DH + cb);
  if (third)
    *reinterpret_cast<short8*>(kbuf[0] + rc * 72 + cc2) = ld8(Kb + (size_t)rc * DH + cc2);
  __syncthreads();

  for (int it = 0; it < NSEQ / 64; ++it) {
    int cur = it & 1;
    bool more = (it + 1 < NSEQ / 64);
    int kc = it * 64;

    // prefetch next K tile into registers (global)
    short8 ka, kb2, kc3;
    if (more) {
      int kn = kc + 64;
      ka  = ld8(Kb + (size_t)(kn + ra) * DH + ca);
      kb2 = ld8(Kb + (size_t)(kn + rb) * DH + cb);
      if (third) kc3 = ld8(Kb + (size_t)(kn + rc) * DH + cc2);
    }

    // V fragments for CURRENT tile, straight from global (L1/L2-resident);
    // issued here, consumed after QK^T+softmax (~300cy of latency cover)
    short8 vf[8];
#pragma unroll
    for (int kt2 = 0; kt2 < 2; ++kt2)
#pragma unroll
      for (int t = 0; t < 4; ++t)
        vf[kt2 * 4 + t] = ld8(vrow + (size_t)t * 16 * NSEQ + kc + kt2 * 32);

    const bf16* kb = kbuf[cur];

    f32x4 s[4];
#pragma unroll
    for (int kt = 0; kt < 4; ++kt) {
      const bf16* kp = kb + (size_t)(kt * 16 + l15) * 72 + quad * 8;
      s[kt] = mfma_bf16(lds8(kp), bq0, z);
      s[kt] = mfma_bf16(lds8(kp + 32), bq1, s[kt]);
    }

    float ls = 0.f;
#pragma unroll
    for (int kt = 0; kt < 4; ++kt) {
      float p0 = EXP2F(s[kt][0]);
      float p1 = EXP2F(s[kt][1]);
      float p2 = EXP2F(s[kt][2]);
      float p3 = EXP2F(s[kt][3]);
      ls += (p0 + p1) + (p2 + p3);
      short4v pk;
      pk[0] = f2b(p0); pk[1] = f2b(p1); pk[2] = f2b(p2); pk[3] = f2b(p3);
      *reinterpret_cast<short4v*>(pb + l15 * 72 + kt * 16 + quad * 4) = pk;
    }
    l_run += ls;

#pragma unroll
    for (int kt2 = 0; kt2 < 2; ++kt2) {
      short8 pfrag = lds8(pb + l15 * 72 + kt2 * 32 + quad * 8);
#pragma unroll
      for (int t = 0; t < 4; ++t)
        o[t] = mfma_bf16(vf[kt2 * 4 + t], pfrag, o[t]);
    }

    if (more) {
      bf16* kn_ = kbuf[1 - cur];
      *reinterpret_cast<short8*>(kn_ + ra * 72 + ca) = ka;
      *reinterpret_cast<short8*>(kn_ + rb * 72 + cb) = kb2;
      if (third) *reinterpret_cast<short8*>(kn_ + rc * 72 + cc2) = kc3;
    }
    __syncthreads();
  }

  l_run += __shfl_xor(l_run, 16);
  l_run += __shfl_xor(l_run, 32);
  float inv = 1.f / l_run;
  int b = bh >> 2, h = bh & 3;
  bf16* orow = AO + ((size_t)b * NSEQ + (m0 + l15)) * CDIM + h * DH;
#pragma unroll
  for (int t = 0; t < 4; ++t) {
    short4v ov;
#pragma unroll
    for (int r = 0; r < 4; ++r) ov[r] = f2b(o[t][r] * inv);
    *reinterpret_cast<short4v*>(orow + t * 16 + quad * 4) = ov;
  }
}

// ---------------- Canonical 128-tile GEMM (r12-validated) ----------------
template <int KD, int EPI, int TI>
__global__ __launch_bounds__(256) void gemm128(const bf16* __restrict__ A, const bf16* __restrict__ Wm,
                                               const bf16* __restrict__ bias, const bf16* __restrict__ res,
                                               bf16* __restrict__ outp, int NC) {
  constexpr int KS = KD / 32;
  constexpr int AR = TI * 32;
  int tid = threadIdx.x;
  int wave = tid >> 6, lane = tid & 63;
  int l15 = lane & 15, quad = lane >> 4;
  int wm = (wave >> 1) * (TI * 16);
  int wn = (wave & 1) * 64;
  int m0 = blockIdx.x * AR;
  int n0 = blockIdx.y * 128;

  __shared__ __align__(16) bf16 abuf[2][AR * 40];
  __shared__ __align__(16) bf16 bbuf[2][128 * 40];

  int sr = tid >> 2, sc = (tid & 3) * 8;

  const bf16* ag[TI / 2];
#pragma unroll
  for (int u = 0; u < TI / 2; ++u) ag[u] = A + (size_t)(m0 + sr + u * 64) * KD + sc;
  const bf16* bg0 = Wm + (size_t)(n0 + sr) * KD + sc;
  const bf16* bg1 = Wm + (size_t)(n0 + 64 + sr) * KD + sc;

  f32x4 z = {0.f, 0.f, 0.f, 0.f};
  f32x4 acc[4][TI];
#pragma unroll
  for (int j = 0; j < 4; ++j)
#pragma unroll
    for (int i = 0; i < TI; ++i) acc[j][i] = z;

#pragma unroll
  for (int u = 0; u < TI / 2; ++u)
    *reinterpret_cast<short8*>(abuf[0] + (sr + u * 64) * 40 + sc) = ld8(ag[u]);
  *reinterpret_cast<short8*>(bbuf[0] + sr * 40 + sc) = ld8(bg0);
  *reinterpret_cast<short8*>(bbuf[0] + (64 + sr) * 40 + sc) = ld8(bg1);
  __syncthreads();

  for (int s = 0; s < KS; ++s) {
    int cur = s & 1;
    bool more = (s + 1 < KS);
    short8 anx[TI / 2], bnx0, bnx1;
    if (more) {
#pragma unroll
      for (int u = 0; u < TI / 2; ++u) anx[u] = ld8(ag[u] + (s + 1) * 32);
      bnx0 = ld8(bg0 + (s + 1) * 32);
      bnx1 = ld8(bg1 + (s + 1) * 32);
    }
    short8 af[TI], bf_[4];
#pragma unroll
    for (int i = 0; i < TI; ++i)
      af[i] = lds8(abuf[cur] + (size_t)(wm + i * 16 + l15) * 40 + quad * 8);
#pragma unroll
    for (int j = 0; j < 4; ++j)
      bf_[j] = lds8(bbuf[cur] + (size_t)(wn + j * 16 + l15) * 40 + quad * 8);
#pragma unroll
    for (int j = 0; j < 4; ++j)
#pragma unroll
      for (int i = 0; i < TI; ++i)
        acc[j][i] = mfma_bf16(bf_[j], af[i], acc[j][i]);
    if (more) {
#pragma unroll
      for (int u = 0; u < TI / 2; ++u)
        *reinterpret_cast<short8*>(abuf[1 - cur] + (sr + u * 64) * 40 + sc) = anx[u];
      *reinterpret_cast<short8*>(bbuf[1 - cur] + sr * 40 + sc) = bnx0;
      *reinterpret_cast<short8*>(bbuf[1 - cur] + (64 + sr) * 40 + sc) = bnx1;
    }
    __syncthreads();
  }

#pragma unroll
  for (int j = 0; j < 4; ++j) {
    int col0 = n0 + wn + j * 16 + quad * 4;
    float bb4[4];
    if (EPI != 0) {
      short4v bl = *reinterpret_cast<const short4v*>(bias + col0);
#pragma unroll
      for (int r = 0; r < 4; ++r) bb4[r] = b2f(bl[r]);
    }
#pragma unroll
    for (int i = 0; i < TI; ++i) {
      size_t idx = (size_t)(m0 + wm + i * 16 + l15) * NC + col0;
      short4v ov;
      if (EPI == 0) {
        short4v rl = *reinterpret_cast<const short4v*>(res + idx);
#pragma unroll
        for (int r = 0; r < 4; ++r) ov[r] = f2b(acc[j][i][r] + b2f(rl[r]));
      } else if (EPI == 1) {
#pragma unroll
        for (int r = 0; r < 4; ++r) {
          float hv = acc[j][i][r] + bb4[r];
          ov[r] = f2b(0.5f * hv * (1.f + erff(hv * 0.70710678118f)));
        }
      } else {
        short4v rl = *reinterpret_cast<const short4v*>(res + idx);
#pragma unroll
        for (int r = 0; r < 4; ++r) ov[r] = f2b(acc[j][i][r] + bb4[r] + b2f(rl[r]));
      }
      *reinterpret_cast<short4v*>(outp + idx) = ov;
    }
  }
}

// ---------------- LayerNorm bf16->bf16 ----------------
__global__ __launch_bounds__(256) void ln_kernel(const bf16* __restrict__ X, const bf16* __restrict__ g,
                                                 const bf16* __restrict__ bv, bf16* __restrict__ out) {
  int row = blockIdx.x * 4 + (threadIdx.x >> 6);
  int lane = threadIdx.x & 63;
  short4v raw = *reinterpret_cast<const short4v*>(X + (size_t)row * CDIM + lane * 4);
  float vv[4];
  float s = 0.f, sq = 0.f;
#pragma unroll
  for (int i = 0; i < 4; ++i) {
    float f = b2f(raw[i]);
    vv[i] = f; s += f; sq += f * f;
  }
#pragma unroll
  for (int off = 1; off < 64; off <<= 1) { s += __shfl_xor(s, off); sq += __shfl_xor(sq, off); }
  float mu = s * (1.f / CDIM);
  float var = sq * (1.f / CDIM) - mu * mu;
  float rstd = rsqrtf(var + 1e-5f);
#pragma unroll
  for (int i = 0; i < 4; ++i) {
    int c = lane * 4 + i;
    out[(size_t)row * CDIM + c] =
        __float2bfloat16((vv[i] - mu) * rstd * __bfloat162float(g[c]) + __bfloat162float(bv[c]));
  }
}

// ---------------- Final LayerNorm, flag-dependent dtype out ----------------
__global__ __launch_bounds__(256) void ln_out_kernel(const bf16* __restrict__ X, const bf16* __restrict__ g,
                                                     const bf16* __restrict__ bv, void* __restrict__ out,
                                                     const int* __restrict__ flag) {
  int is32 = flag[0];
  int row = blockIdx.x * 4 + (threadIdx.x >> 6);
  int lane = threadIdx.x & 63;
  short4v raw = *reinterpret_cast<const short4v*>(X + (size_t)row * CDIM + lane * 4);
  float vv[4];
  float s = 0.f, sq = 0.f;
#pragma unroll
  for (int i = 0; i < 4; ++i) {
    float f = b2f(raw[i]);
    vv[i] = f; s += f; sq += f * f;
  }
#pragma unroll
  for (int off = 1; off < 64; off <<= 1) { s += __shfl_xor(s, off); sq += __shfl_xor(sq, off); }
  float mu = s * (1.f / CDIM);
  float var = sq * (1.f / CDIM) - mu * mu;
  float rstd = rsqrtf(var + 1e-5f);
#pragma unroll
  for (int i = 0; i < 4; ++i) {
    int c = lane * 4 + i;
    size_t idx = (size_t)row * CDIM + c;
    float v = (vv[i] - mu) * rstd * __bfloat162float(g[c]) + __bfloat162float(bv[c]);
    if (is32) ((float*)out)[idx] = v;
    else      ((bf16*)out)[idx] = __float2bfloat16(v);
  }
}

extern "C" void kernel_launch(void* const* d_in, const int* in_sizes, int n_in,
                              void* d_out, int out_size, void* d_ws, size_t ws_size,
                              hipStream_t stream) {
  const int* Wp = (const int*)d_in[12];

  char* ws = (char*)d_ws;
  const size_t SZ = 4718592;  // 2304*4*256 bf16 bytes
  bf16* Qc  = (bf16*)(ws + 0 * SZ);
  bf16* Kc  = (bf16*)(ws + 1 * SZ);
  bf16* Vt  = (bf16*)(ws + 2 * SZ);
  bf16* AO  = (bf16*)(ws + 3 * SZ);
  bf16* F   = (bf16*)(ws + 4 * SZ);
  bf16* Y   = (bf16*)(ws + 5 * SZ);
  bf16* xc  = (bf16*)(ws + 6 * SZ);
  bf16* G   = (bf16*)(ws + 0);              // overlays Qc..AO (4*SZ exactly)
  bf16* Wqkvc  = (bf16*)(ws + 7 * SZ);
  bf16* Wprojc = (bf16*)(ws + 7 * SZ + 393216);
  bf16* W1c    = (bf16*)(ws + 7 * SZ + 524288);
  bf16* W2c    = (bf16*)(ws + 7 * SZ + 1048576);
  bf16* smallc = (bf16*)(ws + 7 * SZ + 1572864);
  bf16* g1c  = smallc + 0;
  bf16* b1c  = smallc + 256;
  bf16* g2c  = smallc + 512;
  bf16* b2c  = smallc + 768;
  bf16* bf1c = smallc + 1024;
  bf16* bf2c = smallc + 2048;
  int*  flagp = (int*)(ws + 7 * SZ + 1581568);
  bf16* outsc = (bf16*)d_out;

  detect_kernel<<<1, 256, 0, stream>>>(d_in[0], flagp);
  cvt_all_kernel<<<3073, 256, 0, stream>>>(d_in[0], d_in[1], d_in[2], d_in[7], d_in[9],
                                           d_in[3], d_in[4], d_in[5], d_in[6], d_in[8], d_in[10],
                                           xc, Wqkvc, Wprojc, W1c, W2c, smallc, flagp);

  qkv_kernel<<<dim3(36, 12), 256, 0, stream>>>(xc, Wqkvc, Qc, Kc, Vt, Wp);
  attn_kernel<<<dim3(16, 48), 192, 0, stream>>>(Qc, Kc, Vt, AO);
  gemm128<256, 0, 2><<<dim3(144, 2), 256, 0, stream>>>(AO, Wprojc, nullptr, xc, outsc, 256);
  ln_kernel<<<2304, 256, 0, stream>>>(outsc, g1c, b1c, F);
  gemm128<256, 1, 4><<<dim3(72, 8), 256, 0, stream>>>(F, W1c, bf1c, nullptr, G, 1024);
  gemm128<1024, 2, 2><<<dim3(144, 2), 256, 0, stream>>>(G, W2c, bf2c, F, Y, 256);
  ln_out_kernel<<<2304, 256, 0, stream>>>(Y, g2c, b2c, d_out, flagp);
}

// Round 2
// 217.747 us; speedup vs baseline: 1.1473x; 1.1473x over previous
//
#include <hip/hip_runtime.h>
#include <hip/hip_bf16.h>
#include <math.h>

typedef __hip_bfloat16 bf16;
typedef __attribute__((ext_vector_type(8))) short short8;
typedef __attribute__((ext_vector_type(4))) short short4v;
typedef __attribute__((ext_vector_type(4))) float f32x4;

#define NSEQ 2304
#define CDIM 256
#define NHD  4
#define DH   64

#if __has_builtin(__builtin_amdgcn_exp2f)
#define EXP2F __builtin_amdgcn_exp2f
#else
#define EXP2F exp2f
#endif

static __device__ __forceinline__ f32x4 mfma_bf16(short8 a, short8 b, f32x4 c) {
  return __builtin_amdgcn_mfma_f32_16x16x32_bf16(a, b, c, 0, 0, 0);
}
static __device__ __forceinline__ short8 ld8(const bf16* p) {
  return *reinterpret_cast<const short8*>(p);
}
static __device__ __forceinline__ short8 lds8(const bf16* p) {
  return *reinterpret_cast<const short8*>(p);
}
static __device__ __forceinline__ float b2f(short v) {
  unsigned int u = ((unsigned int)(unsigned short)v) << 16;
  return __uint_as_float(u);
}
static __device__ __forceinline__ short f2b(float f) {
  bf16 h = __float2bfloat16(f);
  return *reinterpret_cast<short*>(&h);
}

// ---------------- dtype probe ----------------
__global__ __launch_bounds__(256) void detect_kernel(const void* __restrict__ xraw,
                                                     int* __restrict__ flag) {
  int t = threadIdx.x;
  const unsigned short* s = (const unsigned short*)xraw;
  int bad = 0;
#pragma unroll
  for (int i = 0; i < 8; ++i) {
    unsigned idx = (((unsigned)(t * 8 + i)) * 9173u) & ((1u << 20) - 1);
    unsigned short v = s[idx * 2];
    unsigned e = (v >> 7) & 0xFFu;
    if (e > 133u) bad++;
  }
  __shared__ int tot;
  if (t == 0) tot = 0;
  __syncthreads();
  atomicAdd(&tot, bad);
  __syncthreads();
  if (t == 0) flag[0] = (tot >= 16) ? 1 : 0;
}

// ---------------- fused conversion of all float inputs ----------------
__global__ __launch_bounds__(256) void cvt_all_kernel(const void* sx, const void* sqkv, const void* sproj,
                                                      const void* sw1, const void* sw2,
                                                      const void* g1, const void* b1, const void* g2,
                                                      const void* b2, const void* bias1, const void* bias2,
                                                      bf16* dx, bf16* dqkv, bf16* dproj,
                                                      bf16* dw1, bf16* dw2, bf16* dsm,
                                                      const int* __restrict__ flag) {
  int is32 = flag[0];
  int bid = blockIdx.x;
  const void* src; bf16* dst; int i4;
  if (bid < 2304)      { src = sx;    dst = dx;    i4 = bid * 256 + threadIdx.x; }
  else if (bid < 2496) { src = sqkv;  dst = dqkv;  i4 = (bid - 2304) * 256 + threadIdx.x; }
  else if (bid < 2560) { src = sproj; dst = dproj; i4 = (bid - 2496) * 256 + threadIdx.x; }
  else if (bid < 2816) { src = sw1;   dst = dw1;   i4 = (bid - 2560) * 256 + threadIdx.x; }
  else if (bid < 3072) { src = sw2;   dst = dw2;   i4 = (bid - 2816) * 256 + threadIdx.x; }
  else {
    const void* srcs[6] = {g1, b1, g2, b2, bias1, bias2};
    const int ns[6] = {256, 256, 256, 256, 1024, 256};
    const int off[6] = {0, 256, 512, 768, 1024, 2048};
    int t = threadIdx.x;
#pragma unroll
    for (int j = 0; j < 6; ++j)
      for (int i = t; i < ns[j]; i += 256) {
        if (is32) dsm[off[j] + i] = __float2bfloat16(((const float*)srcs[j])[i]);
        else      dsm[off[j] + i] = ((const bf16*)srcs[j])[i];
      }
    return;
  }
  if (is32) {
    float4 v = ((const float4*)src)[i4];
    short4v o;
    o[0] = f2b(v.x); o[1] = f2b(v.y); o[2] = f2b(v.z); o[3] = f2b(v.w);
    ((short4v*)dst)[i4] = o;
  } else {
    ((short4v*)dst)[i4] = ((const short4v*)src)[i4];
  }
}

// ---------------- QKV GEMM with FUSED RoPE epilogue (r13-validated) ----------------
__global__ __launch_bounds__(256, 1) void qkv_kernel(const bf16* __restrict__ X,
                                                     const bf16* __restrict__ Wqkv,
                                                     bf16* __restrict__ Q, bf16* __restrict__ K,
                                                     bf16* __restrict__ Vt,
                                                     const int* __restrict__ Wp) {
  int wave = threadIdx.x >> 6, lane = threadIdx.x & 63;
  int l15 = lane & 15, quad = lane >> 4;
  int m0 = (blockIdx.x * 4 + wave) * 64;
  int n0 = blockIdx.y * 64;
  const bf16* arow = X + (size_t)(m0 + l15) * CDIM + quad * 8;
  const bf16* brow = Wqkv + (size_t)(n0 + l15) * CDIM + quad * 8;
  f32x4 z = {0.f, 0.f, 0.f, 0.f};
  f32x4 acc[4][4];
#pragma unroll
  for (int j = 0; j < 4; ++j)
#pragma unroll
    for (int i = 0; i < 4; ++i) acc[j][i] = z;

  short8 a[4], b[4];
#pragma unroll
  for (int i = 0; i < 4; ++i) a[i] = ld8(arow + (size_t)i * 16 * CDIM);
#pragma unroll
  for (int j = 0; j < 4; ++j) b[j] = ld8(brow + (size_t)j * 16 * CDIM);
#pragma unroll
  for (int kk = 32; kk <= CDIM; kk += 32) {
    short8 an[4], bn[4];
    if (kk < CDIM) {
#pragma unroll
      for (int i = 0; i < 4; ++i) an[i] = ld8(arow + (size_t)i * 16 * CDIM + kk);
#pragma unroll
      for (int j = 0; j < 4; ++j) bn[j] = ld8(brow + (size_t)j * 16 * CDIM + kk);
    }
#pragma unroll
    for (int j = 0; j < 4; ++j)
#pragma unroll
      for (int i = 0; i < 4; ++i) acc[j][i] = mfma_bf16(b[j], a[i], acc[j][i]);
    if (kk < CDIM) {
#pragma unroll
      for (int i = 0; i < 4; ++i) a[i] = an[i];
#pragma unroll
      for (int j = 0; j < 4; ++j) b[j] = bn[j];
    }
  }

  int which = n0 >> 8, h = (n0 & 255) >> 6;
  if (which == 2) {
#pragma unroll
    for (int j = 0; j < 4; ++j) {
      int d0 = j * 16 + quad * 4;
#pragma unroll
      for (int i = 0; i < 4; ++i) {
        int gm = m0 + i * 16 + l15;
        int bb = gm / NSEQ, n = gm % NSEQ;
        int bh = bb * NHD + h;
#pragma unroll
        for (int r = 0; r < 4; ++r)
          Vt[((size_t)bh * DH + d0 + r) * NSEQ + n] = __float2bfloat16(acc[j][i][r]);
      }
    }
  } else {
    int Wv = Wp[0];
    if (Wv <= 0 || Wv > 65536) Wv = 48;
    bf16* dst = (which == 0) ? Q : K;
    const float cc = -0.28782313662425574f;  // -ln(10000)/32
    const float EC1 = 0.7498942434f, EC2 = 0.5623413252f, EC3 = 0.4216965034f;
#pragma unroll
    for (int i = 0; i < 4; ++i) {
      int gm = m0 + i * 16 + l15;
      int bb = gm / NSEQ, n = gm % NSEQ;
      int bh = bb * NHD + h;
      int py = n / Wv, px = n - py * Wv;
#pragma unroll
      for (int j = 0; j < 4; ++j) {
        int d0 = j * 16 + quad * 4;
        float pos = (d0 & 32) ? (float)px : (float)py;
        int base = d0 & 31;
        float fb = __expf(cc * (float)base);
        float f0 = fb, f1 = fb * EC1, f2 = fb * EC2, f3 = fb * EC3;
        float s0, c0, s1, c1, s2, c2, s3, c3;
        __sincosf(pos * f0, &s0, &c0);
        __sincosf(pos * f1, &s1, &c1);
        __sincosf(pos * f2, &s2, &c2);
        __sincosf(pos * f3, &s3, &c3);
        float a0 = acc[j][i][0], a1 = acc[j][i][1], a2 = acc[j][i][2], a3 = acc[j][i][3];
        short4v ov;
        ov[0] = f2b(a0 * c0 - a1 * s0);
        ov[1] = f2b(a1 * c1 + a0 * s1);
        ov[2] = f2b(a2 * c2 - a3 * s2);
        ov[3] = f2b(a3 * c3 + a2 * s3);
        *reinterpret_cast<short4v*>(dst + ((size_t)bh * NSEQ + n) * DH + d0) = ov;
      }
    }
  }
}

// ---------------- Flash attention ----------------
// r0 structure restored (K,V,P via LDS, double-buffered) but each wave now
// computes 32 q-rows (2 q-fragment sets) instead of 16: every K/V ds_read
// feeds 2 MFMAs, cutting LDS read traffic per q-row by 2x. Block = 2 waves
// x 32 rows = same 64-row tile, same grid (16,36), same barrier scheme.
__global__ __launch_bounds__(128, 2) void attn_kernel(const bf16* __restrict__ Q, const bf16* __restrict__ K,
                                                      const bf16* __restrict__ Vt, bf16* __restrict__ AO) {
  int bh = blockIdx.x, qt = blockIdx.y;
  int tid = threadIdx.x;
  int wave = tid >> 6, lane = tid & 63;
  int l15 = lane & 15, quad = lane >> 4;
  int m0 = qt * 64 + wave * 32;
  const bf16* Qb = Q + (size_t)bh * NSEQ * DH;
  const bf16* Kb = K + (size_t)bh * NSEQ * DH;
  const bf16* Vb = Vt + (size_t)bh * DH * NSEQ;

  __shared__ __align__(16) bf16 kbuf[2][64 * 72];
  __shared__ __align__(16) bf16 vbuf[2][64 * 72];
  __shared__ __align__(16) bf16 plds[2][32 * 72];

  // staging map: 64x64 K tile + 64x64 V tile = 2x512 short8 slots over 128
  // threads -> 4 K slots + 4 V slots per thread
  int rs[4], cs[4];
#pragma unroll
  for (int j = 0; j < 4; ++j) {
    int i = tid + j * 128;
    rs[j] = i >> 3;
    cs[j] = (i & 7) * 8;
  }

  // Q pre-scaled by 0.125 * log2(e) so p = exp2(s) directly
  const float QS = 0.18033688011112042f;
  short8 qa0 = ld8(Qb + (size_t)(m0 + l15) * DH + quad * 8);
  short8 qa1 = ld8(Qb + (size_t)(m0 + l15) * DH + 32 + quad * 8);
  short8 qb0 = ld8(Qb + (size_t)(m0 + 16 + l15) * DH + quad * 8);
  short8 qb1 = ld8(Qb + (size_t)(m0 + 16 + l15) * DH + 32 + quad * 8);
#pragma unroll
  for (int i = 0; i < 8; ++i) {
    qa0[i] = f2b(b2f(qa0[i]) * QS);
    qa1[i] = f2b(b2f(qa1[i]) * QS);
    qb0[i] = f2b(b2f(qb0[i]) * QS);
    qb1[i] = f2b(b2f(qb1[i]) * QS);
  }

  f32x4 z = {0.f, 0.f, 0.f, 0.f};
  f32x4 o[4] = {z, z, z, z};
  f32x4 o2[4] = {z, z, z, z};
  float l_run = 0.f, l_run2 = 0.f;
  bf16* pb = plds[wave];

  // stage K/V tile 0
#pragma unroll
  for (int j = 0; j < 4; ++j) {
    *reinterpret_cast<short8*>(kbuf[0] + rs[j] * 72 + cs[j]) = ld8(Kb + (size_t)rs[j] * DH + cs[j]);
    *reinterpret_cast<short8*>(vbuf[0] + rs[j] * 72 + cs[j]) = ld8(Vb + (size_t)rs[j] * NSEQ + cs[j]);
  }
  __syncthreads();

  for (int it = 0; it < NSEQ / 64; ++it) {
    int cur = it & 1;
    bool more = (it + 1 < NSEQ / 64);

    // prefetch next K/V tile into registers (global)
    short8 kpre[4], vpre[4];
    if (more) {
      int kn = (it + 1) * 64;
#pragma unroll
      for (int j = 0; j < 4; ++j) {
        kpre[j] = ld8(Kb + (size_t)(kn + rs[j]) * DH + cs[j]);
        vpre[j] = ld8(Vb + (size_t)rs[j] * NSEQ + kn + cs[j]);
      }
    }

    const bf16* kb = kbuf[cur];
    const bf16* vb = vbuf[cur];

    f32x4 s[4], s2[4];
#pragma unroll
    for (int kt = 0; kt < 4; ++kt) {
      const bf16* kp = kb + (size_t)(kt * 16 + l15) * 72 + quad * 8;
      short8 kf0 = lds8(kp);
      short8 kf1 = lds8(kp + 32);
      s[kt] = mfma_bf16(kf0, qa0, z);
      s[kt] = mfma_bf16(kf1, qa1, s[kt]);
      s2[kt] = mfma_bf16(kf0, qb0, z);
      s2[kt] = mfma_bf16(kf1, qb1, s2[kt]);
    }

    float ls = 0.f, ls2 = 0.f;
#pragma unroll
    for (int kt = 0; kt < 4; ++kt) {
      float p0 = EXP2F(s[kt][0]);
      float p1 = EXP2F(s[kt][1]);
      float p2 = EXP2F(s[kt][2]);
      float p3 = EXP2F(s[kt][3]);
      ls += (p0 + p1) + (p2 + p3);
      short4v pk;
      pk[0] = f2b(p0); pk[1] = f2b(p1); pk[2] = f2b(p2); pk[3] = f2b(p3);
      *reinterpret_cast<short4v*>(pb + l15 * 72 + kt * 16 + quad * 4) = pk;
      float q0 = EXP2F(s2[kt][0]);
      float q1 = EXP2F(s2[kt][1]);
      float q2 = EXP2F(s2[kt][2]);
      float q3 = EXP2F(s2[kt][3]);
      ls2 += (q0 + q1) + (q2 + q3);
      short4v pk2;
      pk2[0] = f2b(q0); pk2[1] = f2b(q1); pk2[2] = f2b(q2); pk2[3] = f2b(q3);
      *reinterpret_cast<short4v*>(pb + (16 + l15) * 72 + kt * 16 + quad * 4) = pk2;
    }
    l_run += ls;
    l_run2 += ls2;

#pragma unroll
    for (int kt2 = 0; kt2 < 2; ++kt2) {
      short8 pfA = lds8(pb + l15 * 72 + kt2 * 32 + quad * 8);
      short8 pfB = lds8(pb + (16 + l15) * 72 + kt2 * 32 + quad * 8);
#pragma unroll
      for (int t = 0; t < 4; ++t) {
        short8 vf = lds8(vb + (size_t)(t * 16 + l15) * 72 + kt2 * 32 + quad * 8);
        o[t] = mfma_bf16(vf, pfA, o[t]);
        o2[t] = mfma_bf16(vf, pfB, o2[t]);
      }
    }

    if (more) {
      bf16* kn_ = kbuf[1 - cur];
      bf16* vn_ = vbuf[1 - cur];
#pragma unroll
      for (int j = 0; j < 4; ++j) {
        *reinterpret_cast<short8*>(kn_ + rs[j] * 72 + cs[j]) = kpre[j];
        *reinterpret_cast<short8*>(vn_ + rs[j] * 72 + cs[j]) = vpre[j];
      }
    }
    __syncthreads();
  }

  l_run += __shfl_xor(l_run, 16);
  l_run += __shfl_xor(l_run, 32);
  l_run2 += __shfl_xor(l_run2, 16);
  l_run2 += __shfl_xor(l_run2, 32);
  float inv = 1.f / l_run;
  float inv2 = 1.f / l_run2;
  int b = bh >> 2, h = bh & 3;
  bf16* orow = AO + ((size_t)b * NSEQ + (m0 + l15)) * CDIM + h * DH;
  bf16* orow2 = AO + ((size_t)b * NSEQ + (m0 + 16 + l15)) * CDIM + h * DH;
#pragma unroll
  for (int t = 0; t < 4; ++t) {
    short4v ov, ov2;
#pragma unroll
    for (int r = 0; r < 4; ++r) {
      ov[r] = f2b(o[t][r] * inv);
      ov2[r] = f2b(o2[t][r] * inv2);
    }
    *reinterpret_cast<short4v*>(orow + t * 16 + quad * 4) = ov;
    *reinterpret_cast<short4v*>(orow2 + t * 16 + quad * 4) = ov2;
  }
}

// ---------------- Canonical 128-tile GEMM (r12-validated) ----------------
template <int KD, int EPI, int TI>
__global__ __launch_bounds__(256) void gemm128(const bf16* __restrict__ A, const bf16* __restrict__ Wm,
                                               const bf16* __restrict__ bias, const bf16* __restrict__ res,
                                               bf16* __restrict__ outp, int NC) {
  constexpr int KS = KD / 32;
  constexpr int AR = TI * 32;
  int tid = threadIdx.x;
  int wave = tid >> 6, lane = tid & 63;
  int l15 = lane & 15, quad = lane >> 4;
  int wm = (wave >> 1) * (TI * 16);
  int wn = (wave & 1) * 64;
  int m0 = blockIdx.x * AR;
  int n0 = blockIdx.y * 128;

  __shared__ __align__(16) bf16 abuf[2][AR * 40];
  __shared__ __align__(16) bf16 bbuf[2][128 * 40];

  int sr = tid >> 2, sc = (tid & 3) * 8;

  const bf16* ag[TI / 2];
#pragma unroll
  for (int u = 0; u < TI / 2; ++u) ag[u] = A + (size_t)(m0 + sr + u * 64) * KD + sc;
  const bf16* bg0 = Wm + (size_t)(n0 + sr) * KD + sc;
  const bf16* bg1 = Wm + (size_t)(n0 + 64 + sr) * KD + sc;

  f32x4 z = {0.f, 0.f, 0.f, 0.f};
  f32x4 acc[4][TI];
#pragma unroll
  for (int j = 0; j < 4; ++j)
#pragma unroll
    for (int i = 0; i < TI; ++i) acc[j][i] = z;

#pragma unroll
  for (int u = 0; u < TI / 2; ++u)
    *reinterpret_cast<short8*>(abuf[0] + (sr + u * 64) * 40 + sc) = ld8(ag[u]);
  *reinterpret_cast<short8*>(bbuf[0] + sr * 40 + sc) = ld8(bg0);
  *reinterpret_cast<short8*>(bbuf[0] + (64 + sr) * 40 + sc) = ld8(bg1);
  __syncthreads();

  for (int s = 0; s < KS; ++s) {
    int cur = s & 1;
    bool more = (s + 1 < KS);
    short8 anx[TI / 2], bnx0, bnx1;
    if (more) {
#pragma unroll
      for (int u = 0; u < TI / 2; ++u) anx[u] = ld8(ag[u] + (s + 1) * 32);
      bnx0 = ld8(bg0 + (s + 1) * 32);
      bnx1 = ld8(bg1 + (s + 1) * 32);
    }
    short8 af[TI], bf_[4];
#pragma unroll
    for (int i = 0; i < TI; ++i)
      af[i] = lds8(abuf[cur] + (size_t)(wm + i * 16 + l15) * 40 + quad * 8);
#pragma unroll
    for (int j = 0; j < 4; ++j)
      bf_[j] = lds8(bbuf[cur] + (size_t)(wn + j * 16 + l15) * 40 + quad * 8);
#pragma unroll
    for (int j = 0; j < 4; ++j)
#pragma unroll
      for (int i = 0; i < TI; ++i)
        acc[j][i] = mfma_bf16(bf_[j], af[i], acc[j][i]);
    if (more) {
#pragma unroll
      for (int u = 0; u < TI / 2; ++u)
        *reinterpret_cast<short8*>(abuf[1 - cur] + (sr + u * 64) * 40 + sc) = anx[u];
      *reinterpret_cast<short8*>(bbuf[1 - cur] + sr * 40 + sc) = bnx0;
      *reinterpret_cast<short8*>(bbuf[1 - cur] + (64 + sr) * 40 + sc) = bnx1;
    }
    __syncthreads();
  }

#pragma unroll
  for (int j = 0; j < 4; ++j) {
    int col0 = n0 + wn + j * 16 + quad * 4;
    float bb4[4];
    if (EPI != 0) {
      short4v bl = *reinterpret_cast<const short4v*>(bias + col0);
#pragma unroll
      for (int r = 0; r < 4; ++r) bb4[r] = b2f(bl[r]);
    }
#pragma unroll
    for (int i = 0; i < TI; ++i) {
      size_t idx = (size_t)(m0 + wm + i * 16 + l15) * NC + col0;
      short4v ov;
      if (EPI == 0) {
        short4v rl = *reinterpret_cast<const short4v*>(res + idx);
#pragma unroll
        for (int r = 0; r < 4; ++r) ov[r] = f2b(acc[j][i][r] + b2f(rl[r]));
      } else if (EPI == 1) {
#pragma unroll
        for (int r = 0; r < 4; ++r) {
          float hv = acc[j][i][r] + bb4[r];
          ov[r] = f2b(0.5f * hv * (1.f + erff(hv * 0.70710678118f)));
        }
      } else {
        short4v rl = *reinterpret_cast<const short4v*>(res + idx);
#pragma unroll
        for (int r = 0; r < 4; ++r) ov[r] = f2b(acc[j][i][r] + bb4[r] + b2f(rl[r]));
      }
      *reinterpret_cast<short4v*>(outp + idx) = ov;
    }
  }
}

// ---------------- LayerNorm bf16->bf16 ----------------
__global__ __launch_bounds__(256) void ln_kernel(const bf16* __restrict__ X, const bf16* __restrict__ g,
                                                 const bf16* __restrict__ bv, bf16* __restrict__ out) {
  int row = blockIdx.x * 4 + (threadIdx.x >> 6);
  int lane = threadIdx.x & 63;
  short4v raw = *reinterpret_cast<const short4v*>(X + (size_t)row * CDIM + lane * 4);
  float vv[4];
  float s = 0.f, sq = 0.f;
#pragma unroll
  for (int i = 0; i < 4; ++i) {
    float f = b2f(raw[i]);
    vv[i] = f; s += f; sq += f * f;
  }
#pragma unroll
  for (int off = 1; off < 64; off <<= 1) { s += __shfl_xor(s, off); sq += __shfl_xor(sq, off); }
  float mu = s * (1.f / CDIM);
  float var = sq * (1.f / CDIM) - mu * mu;
  float rstd = rsqrtf(var + 1e-5f);
#pragma unroll
  for (int i = 0; i < 4; ++i) {
    int c = lane * 4 + i;
    out[(size_t)row * CDIM + c] =
        __float2bfloat16((vv[i] - mu) * rstd * __bfloat162float(g[c]) + __bfloat162float(bv[c]));
  }
}

// ---------------- Final LayerNorm, flag-dependent dtype out ----------------
__global__ __launch_bounds__(256) void ln_out_kernel(const bf16* __restrict__ X, const bf16* __restrict__ g,
                                                     const bf16* __restrict__ bv, void* __restrict__ out,
                                                     const int* __restrict__ flag) {
  int is32 = flag[0];
  int row = blockIdx.x * 4 + (threadIdx.x >> 6);
  int lane = threadIdx.x & 63;
  short4v raw = *reinterpret_cast<const short4v*>(X + (size_t)row * CDIM + lane * 4);
  float vv[4];
  float s = 0.f, sq = 0.f;
#pragma unroll
  for (int i = 0; i < 4; ++i) {
    float f = b2f(raw[i]);
    vv[i] = f; s += f; sq += f * f;
  }
#pragma unroll
  for (int off = 1; off < 64; off <<= 1) { s += __shfl_xor(s, off); sq += __shfl_xor(sq, off); }
  float mu = s * (1.f / CDIM);
  float var = sq * (1.f / CDIM) - mu * mu;
  float rstd = rsqrtf(var + 1e-5f);
#pragma unroll
  for (int i = 0; i < 4; ++i) {
    int c = lane * 4 + i;
    size_t idx = (size_t)row * CDIM + c;
    float v = (vv[i] - mu) * rstd * __bfloat162float(g[c]) + __bfloat162float(bv[c]);
    if (is32) ((float*)out)[idx] = v;
    else      ((bf16*)out)[idx] = __float2bfloat16(v);
  }
}

extern "C" void kernel_launch(void* const* d_in, const int* in_sizes, int n_in,
                              void* d_out, int out_size, void* d_ws, size_t ws_size,
                              hipStream_t stream) {
  const int* Wp = (const int*)d_in[12];

  char* ws = (char*)d_ws;
  const size_t SZ = 4718592;  // 2304*4*256 bf16 bytes
  bf16* Qc  = (bf16*)(ws + 0 * SZ);
  bf16* Kc  = (bf16*)(ws + 1 * SZ);
  bf16* Vt  = (bf16*)(ws + 2 * SZ);
  bf16* AO  = (bf16*)(ws + 3 * SZ);
  bf16* F   = (bf16*)(ws + 4 * SZ);
  bf16* Y   = (bf16*)(ws + 5 * SZ);
  bf16* xc  = (bf16*)(ws + 6 * SZ);
  bf16* G   = (bf16*)(ws + 0);              // overlays Qc..AO (4*SZ exactly)
  bf16* Wqkvc  = (bf16*)(ws + 7 * SZ);
  bf16* Wprojc = (bf16*)(ws + 7 * SZ + 393216);
  bf16* W1c    = (bf16*)(ws + 7 * SZ + 524288);
  bf16* W2c    = (bf16*)(ws + 7 * SZ + 1048576);
  bf16* smallc = (bf16*)(ws + 7 * SZ + 1572864);
  bf16* g1c  = smallc + 0;
  bf16* b1c  = smallc + 256;
  bf16* g2c  = smallc + 512;
  bf16* b2c  = smallc + 768;
  bf16* bf1c = smallc + 1024;
  bf16* bf2c = smallc + 2048;
  int*  flagp = (int*)(ws + 7 * SZ + 1581568);
  bf16* outsc = (bf16*)d_out;

  detect_kernel<<<1, 256, 0, stream>>>(d_in[0], flagp);
  cvt_all_kernel<<<3073, 256, 0, stream>>>(d_in[0], d_in[1], d_in[2], d_in[7], d_in[9],
                                           d_in[3], d_in[4], d_in[5], d_in[6], d_in[8], d_in[10],
                                           xc, Wqkvc, Wprojc, W1c, W2c, smallc, flagp);

  qkv_kernel<<<dim3(36, 12), 256, 0, stream>>>(xc, Wqkvc, Qc, Kc, Vt, Wp);
  attn_kernel<<<dim3(16, 36), 128, 0, stream>>>(Qc, Kc, Vt, AO);
  gemm128<256, 0, 2><<<dim3(144, 2), 256, 0, stream>>>(AO, Wprojc, nullptr, xc, outsc, 256);
  ln_kernel<<<2304, 256, 0, stream>>>(outsc, g1c, b1c, F);
  gemm128<256, 1, 4><<<dim3(72, 8), 256, 0, stream>>>(F, W1c, bf1c, nullptr, G, 1024);
  gemm128<1024, 2, 2><<<dim3(144, 2), 256, 0, stream>>>(G, W2c, bf2c, F, Y, 256);
  ln_out_kernel<<<2304, 256, 0, stream>>>(Y, g2c, b2c, d_out, flagp);
}

// Round 3
// 212.407 us; speedup vs baseline: 1.1761x; 1.0251x over previous
//
#include <hip/hip_runtime.h>
#include <hip/hip_bf16.h>
#include <math.h>

typedef __hip_bfloat16 bf16;
typedef __attribute__((ext_vector_type(8))) short short8;
typedef __attribute__((ext_vector_type(4))) short short4v;
typedef __attribute__((ext_vector_type(4))) float f32x4;

#define NSEQ 2304
#define CDIM 256
#define NHD  4
#define DH   64

#if __has_builtin(__builtin_amdgcn_exp2f)
#define EXP2F __builtin_amdgcn_exp2f
#else
#define EXP2F exp2f
#endif

static __device__ __forceinline__ f32x4 mfma_bf16(short8 a, short8 b, f32x4 c) {
  return __builtin_amdgcn_mfma_f32_16x16x32_bf16(a, b, c, 0, 0, 0);
}
static __device__ __forceinline__ short8 ld8(const bf16* p) {
  return *reinterpret_cast<const short8*>(p);
}
static __device__ __forceinline__ short8 lds8(const bf16* p) {
  return *reinterpret_cast<const short8*>(p);
}
static __device__ __forceinline__ float b2f(short v) {
  unsigned int u = ((unsigned int)(unsigned short)v) << 16;
  return __uint_as_float(u);
}
static __device__ __forceinline__ short f2b(float f) {
  bf16 h = __float2bfloat16(f);
  return *reinterpret_cast<short*>(&h);
}

// ---------------- dtype probe ----------------
__global__ __launch_bounds__(256) void detect_kernel(const void* __restrict__ xraw,
                                                     int* __restrict__ flag) {
  int t = threadIdx.x;
  const unsigned short* s = (const unsigned short*)xraw;
  int bad = 0;
#pragma unroll
  for (int i = 0; i < 8; ++i) {
    unsigned idx = (((unsigned)(t * 8 + i)) * 9173u) & ((1u << 20) - 1);
    unsigned short v = s[idx * 2];
    unsigned e = (v >> 7) & 0xFFu;
    if (e > 133u) bad++;
  }
  __shared__ int tot;
  if (t == 0) tot = 0;
  __syncthreads();
  atomicAdd(&tot, bad);
  __syncthreads();
  if (t == 0) flag[0] = (tot >= 16) ? 1 : 0;
}

// ---------------- fused conversion of all float inputs ----------------
__global__ __launch_bounds__(256) void cvt_all_kernel(const void* sx, const void* sqkv, const void* sproj,
                                                      const void* sw1, const void* sw2,
                                                      const void* g1, const void* b1, const void* g2,
                                                      const void* b2, const void* bias1, const void* bias2,
                                                      bf16* dx, bf16* dqkv, bf16* dproj,
                                                      bf16* dw1, bf16* dw2, bf16* dsm,
                                                      const int* __restrict__ flag) {
  int is32 = flag[0];
  int bid = blockIdx.x;
  const void* src; bf16* dst; int i4;
  if (bid < 2304)      { src = sx;    dst = dx;    i4 = bid * 256 + threadIdx.x; }
  else if (bid < 2496) { src = sqkv;  dst = dqkv;  i4 = (bid - 2304) * 256 + threadIdx.x; }
  else if (bid < 2560) { src = sproj; dst = dproj; i4 = (bid - 2496) * 256 + threadIdx.x; }
  else if (bid < 2816) { src = sw1;   dst = dw1;   i4 = (bid - 2560) * 256 + threadIdx.x; }
  else if (bid < 3072) { src = sw2;   dst = dw2;   i4 = (bid - 2816) * 256 + threadIdx.x; }
  else {
    const void* srcs[6] = {g1, b1, g2, b2, bias1, bias2};
    const int ns[6] = {256, 256, 256, 256, 1024, 256};
    const int off[6] = {0, 256, 512, 768, 1024, 2048};
    int t = threadIdx.x;
#pragma unroll
    for (int j = 0; j < 6; ++j)
      for (int i = t; i < ns[j]; i += 256) {
        if (is32) dsm[off[j] + i] = __float2bfloat16(((const float*)srcs[j])[i]);
        else      dsm[off[j] + i] = ((const bf16*)srcs[j])[i];
      }
    return;
  }
  if (is32) {
    float4 v = ((const float4*)src)[i4];
    short4v o;
    o[0] = f2b(v.x); o[1] = f2b(v.y); o[2] = f2b(v.z); o[3] = f2b(v.w);
    ((short4v*)dst)[i4] = o;
  } else {
    ((short4v*)dst)[i4] = ((const short4v*)src)[i4];
  }
}

// ---------------- QKV GEMM with FUSED RoPE epilogue (r13-validated) ----------------
__global__ __launch_bounds__(256, 1) void qkv_kernel(const bf16* __restrict__ X,
                                                     const bf16* __restrict__ Wqkv,
                                                     bf16* __restrict__ Q, bf16* __restrict__ K,
                                                     bf16* __restrict__ Vt,
                                                     const int* __restrict__ Wp) {
  int wave = threadIdx.x >> 6, lane = threadIdx.x & 63;
  int l15 = lane & 15, quad = lane >> 4;
  int m0 = (blockIdx.x * 4 + wave) * 64;
  int n0 = blockIdx.y * 64;
  const bf16* arow = X + (size_t)(m0 + l15) * CDIM + quad * 8;
  const bf16* brow = Wqkv + (size_t)(n0 + l15) * CDIM + quad * 8;
  f32x4 z = {0.f, 0.f, 0.f, 0.f};
  f32x4 acc[4][4];
#pragma unroll
  for (int j = 0; j < 4; ++j)
#pragma unroll
    for (int i = 0; i < 4; ++i) acc[j][i] = z;

  short8 a[4], b[4];
#pragma unroll
  for (int i = 0; i < 4; ++i) a[i] = ld8(arow + (size_t)i * 16 * CDIM);
#pragma unroll
  for (int j = 0; j < 4; ++j) b[j] = ld8(brow + (size_t)j * 16 * CDIM);
#pragma unroll
  for (int kk = 32; kk <= CDIM; kk += 32) {
    short8 an[4], bn[4];
    if (kk < CDIM) {
#pragma unroll
      for (int i = 0; i < 4; ++i) an[i] = ld8(arow + (size_t)i * 16 * CDIM + kk);
#pragma unroll
      for (int j = 0; j < 4; ++j) bn[j] = ld8(brow + (size_t)j * 16 * CDIM + kk);
    }
#pragma unroll
    for (int j = 0; j < 4; ++j)
#pragma unroll
      for (int i = 0; i < 4; ++i) acc[j][i] = mfma_bf16(b[j], a[i], acc[j][i]);
    if (kk < CDIM) {
#pragma unroll
      for (int i = 0; i < 4; ++i) a[i] = an[i];
#pragma unroll
      for (int j = 0; j < 4; ++j) b[j] = bn[j];
    }
  }

  int which = n0 >> 8, h = (n0 & 255) >> 6;
  if (which == 2) {
#pragma unroll
    for (int j = 0; j < 4; ++j) {
      int d0 = j * 16 + quad * 4;
#pragma unroll
      for (int i = 0; i < 4; ++i) {
        int gm = m0 + i * 16 + l15;
        int bb = gm / NSEQ, n = gm % NSEQ;
        int bh = bb * NHD + h;
#pragma unroll
        for (int r = 0; r < 4; ++r)
          Vt[((size_t)bh * DH + d0 + r) * NSEQ + n] = __float2bfloat16(acc[j][i][r]);
      }
    }
  } else {
    int Wv = Wp[0];
    if (Wv <= 0 || Wv > 65536) Wv = 48;
    bf16* dst = (which == 0) ? Q : K;
    const float cc = -0.28782313662425574f;  // -ln(10000)/32
    const float EC1 = 0.7498942434f, EC2 = 0.5623413252f, EC3 = 0.4216965034f;
#pragma unroll
    for (int i = 0; i < 4; ++i) {
      int gm = m0 + i * 16 + l15;
      int bb = gm / NSEQ, n = gm % NSEQ;
      int bh = bb * NHD + h;
      int py = n / Wv, px = n - py * Wv;
#pragma unroll
      for (int j = 0; j < 4; ++j) {
        int d0 = j * 16 + quad * 4;
        float pos = (d0 & 32) ? (float)px : (float)py;
        int base = d0 & 31;
        float fb = __expf(cc * (float)base);
        float f0 = fb, f1 = fb * EC1, f2 = fb * EC2, f3 = fb * EC3;
        float s0, c0, s1, c1, s2, c2, s3, c3;
        __sincosf(pos * f0, &s0, &c0);
        __sincosf(pos * f1, &s1, &c1);
        __sincosf(pos * f2, &s2, &c2);
        __sincosf(pos * f3, &s3, &c3);
        float a0 = acc[j][i][0], a1 = acc[j][i][1], a2 = acc[j][i][2], a3 = acc[j][i][3];
        short4v ov;
        ov[0] = f2b(a0 * c0 - a1 * s0);
        ov[1] = f2b(a1 * c1 + a0 * s1);
        ov[2] = f2b(a2 * c2 - a3 * s2);
        ov[3] = f2b(a3 * c3 + a2 * s3);
        *reinterpret_cast<short4v*>(dst + ((size_t)bh * NSEQ + n) * DH + d0) = ov;
      }
    }
  }
}

// ---------------- Flash attention ----------------
// Intra-block K-split: block = 4 waves over a 64-q-row tile. Wave w owns
// q-half (w&1, 32 rows) and k-slice (w>>1, 32 of the 64 staged k-columns).
// All 4 waves share one staged K/V tile (staging cost = r2), each wave does
// half the k-work of r2's waves (half the exp2 chain, half the frag reads)
// -> r2's 2x read-reuse AND r0's 12 waves/CU occupancy simultaneously.
// Partial o/l of the two k-slices are summed once at the end via LDS
// scratch (kbuf is dead after the main loop).
__global__ __launch_bounds__(256, 3) void attn_kernel(const bf16* __restrict__ Q, const bf16* __restrict__ K,
                                                      const bf16* __restrict__ Vt, bf16* __restrict__ AO) {
  int bh = blockIdx.x, qt = blockIdx.y;
  int tid = threadIdx.x;
  int wave = tid >> 6, lane = tid & 63;
  int l15 = lane & 15, quad = lane >> 4;
  int qf = wave & 1;   // q half: rows [qf*32, qf*32+32)
  int ks = wave >> 1;  // k slice: cols [ks*32, ks*32+32) of each 64-tile
  int m0 = qt * 64 + qf * 32;
  const bf16* Qb = Q + (size_t)bh * NSEQ * DH;
  const bf16* Kb = K + (size_t)bh * NSEQ * DH;
  const bf16* Vb = Vt + (size_t)bh * DH * NSEQ;

  __shared__ __align__(16) bf16 kbuf[2][64 * 72];
  __shared__ __align__(16) bf16 vbuf[2][64 * 72];
  __shared__ __align__(16) bf16 plds[4][32 * 40];

  // staging: 256 threads cover 512 short8 slots per tile (2 K + 2 V each)
  int r1 = tid >> 3, c1 = (tid & 7) * 8;
  int r1b = r1 + 32;

  // Q pre-scaled by 0.125 * log2(e) so p = exp2(s) directly
  const float QS = 0.18033688011112042f;
  short8 qa0 = ld8(Qb + (size_t)(m0 + l15) * DH + quad * 8);
  short8 qa1 = ld8(Qb + (size_t)(m0 + l15) * DH + 32 + quad * 8);
  short8 qb0 = ld8(Qb + (size_t)(m0 + 16 + l15) * DH + quad * 8);
  short8 qb1 = ld8(Qb + (size_t)(m0 + 16 + l15) * DH + 32 + quad * 8);
#pragma unroll
  for (int i = 0; i < 8; ++i) {
    qa0[i] = f2b(b2f(qa0[i]) * QS);
    qa1[i] = f2b(b2f(qa1[i]) * QS);
    qb0[i] = f2b(b2f(qb0[i]) * QS);
    qb1[i] = f2b(b2f(qb1[i]) * QS);
  }

  f32x4 z = {0.f, 0.f, 0.f, 0.f};
  f32x4 o[4] = {z, z, z, z};
  f32x4 o2[4] = {z, z, z, z};
  float l_run = 0.f, l_run2 = 0.f;
  bf16* pb = plds[wave];

  // stage K/V tile 0
  *reinterpret_cast<short8*>(kbuf[0] + r1 * 72 + c1)  = ld8(Kb + (size_t)r1 * DH + c1);
  *reinterpret_cast<short8*>(kbuf[0] + r1b * 72 + c1) = ld8(Kb + (size_t)r1b * DH + c1);
  *reinterpret_cast<short8*>(vbuf[0] + r1 * 72 + c1)  = ld8(Vb + (size_t)r1 * NSEQ + c1);
  *reinterpret_cast<short8*>(vbuf[0] + r1b * 72 + c1) = ld8(Vb + (size_t)r1b * NSEQ + c1);
  __syncthreads();

  for (int it = 0; it < NSEQ / 64; ++it) {
    int cur = it & 1;
    bool more = (it + 1 < NSEQ / 64);

    // prefetch next K/V tile into registers (global)
    short8 kpA, kpB, vpA, vpB;
    if (more) {
      int kn = (it + 1) * 64;
      kpA = ld8(Kb + (size_t)(kn + r1) * DH + c1);
      kpB = ld8(Kb + (size_t)(kn + r1b) * DH + c1);
      vpA = ld8(Vb + (size_t)r1 * NSEQ + kn + c1);
      vpB = ld8(Vb + (size_t)r1b * NSEQ + kn + c1);
    }

    const bf16* kb = kbuf[cur];
    const bf16* vb = vbuf[cur];

    // QK^T for this wave's 32 k-rows x 32 q-rows
    f32x4 s[2], s2[2];
#pragma unroll
    for (int kt = 0; kt < 2; ++kt) {
      const bf16* kp = kb + (size_t)(ks * 32 + kt * 16 + l15) * 72 + quad * 8;
      short8 kf0 = lds8(kp);
      short8 kf1 = lds8(kp + 32);
      s[kt] = mfma_bf16(kf0, qa0, z);
      s[kt] = mfma_bf16(kf1, qa1, s[kt]);
      s2[kt] = mfma_bf16(kf0, qb0, z);
      s2[kt] = mfma_bf16(kf1, qb1, s2[kt]);
    }

    float ls = 0.f, ls2 = 0.f;
#pragma unroll
    for (int kt = 0; kt < 2; ++kt) {
      float p0 = EXP2F(s[kt][0]);
      float p1 = EXP2F(s[kt][1]);
      float p2 = EXP2F(s[kt][2]);
      float p3 = EXP2F(s[kt][3]);
      ls += (p0 + p1) + (p2 + p3);
      short4v pk;
      pk[0] = f2b(p0); pk[1] = f2b(p1); pk[2] = f2b(p2); pk[3] = f2b(p3);
      *reinterpret_cast<short4v*>(pb + l15 * 40 + kt * 16 + quad * 4) = pk;
      float q0 = EXP2F(s2[kt][0]);
      float q1 = EXP2F(s2[kt][1]);
      float q2 = EXP2F(s2[kt][2]);
      float q3 = EXP2F(s2[kt][3]);
      ls2 += (q0 + q1) + (q2 + q3);
      short4v pk2;
      pk2[0] = f2b(q0); pk2[1] = f2b(q1); pk2[2] = f2b(q2); pk2[3] = f2b(q3);
      *reinterpret_cast<short4v*>(pb + (16 + l15) * 40 + kt * 16 + quad * 4) = pk2;
    }
    l_run += ls;
    l_run2 += ls2;

    // PV for this wave's 32 k-cols (partial o over the k-slice)
    {
      short8 pfA = lds8(pb + l15 * 40 + quad * 8);
      short8 pfB = lds8(pb + (16 + l15) * 40 + quad * 8);
#pragma unroll
      for (int t = 0; t < 4; ++t) {
        short8 vf = lds8(vb + (size_t)(t * 16 + l15) * 72 + ks * 32 + quad * 8);
        o[t] = mfma_bf16(vf, pfA, o[t]);
        o2[t] = mfma_bf16(vf, pfB, o2[t]);
      }
    }

    if (more) {
      bf16* kn_ = kbuf[1 - cur];
      bf16* vn_ = vbuf[1 - cur];
      *reinterpret_cast<short8*>(kn_ + r1 * 72 + c1)  = kpA;
      *reinterpret_cast<short8*>(kn_ + r1b * 72 + c1) = kpB;
      *reinterpret_cast<short8*>(vn_ + r1 * 72 + c1)  = vpA;
      *reinterpret_cast<short8*>(vn_ + r1b * 72 + c1) = vpB;
    }
    __syncthreads();
  }

  // ---- cross-kslice combine via LDS scratch (kbuf is dead now) ----
  float* scr = (float*)kbuf;
  int slot = qf * 64 + lane;  // wave2 pairs wave0 (qf=0), wave3 pairs wave1
  if (ks == 1) {
    float* p = scr + slot * 36;
#pragma unroll
    for (int t = 0; t < 4; ++t) {
      *reinterpret_cast<f32x4*>(p + t * 4) = o[t];
      *reinterpret_cast<f32x4*>(p + 16 + t * 4) = o2[t];
    }
    p[32] = l_run;
    p[33] = l_run2;
  }
  __syncthreads();
  if (ks == 0) {
    float* p = scr + slot * 36;
#pragma unroll
    for (int t = 0; t < 4; ++t) {
      f32x4 pa = *reinterpret_cast<f32x4*>(p + t * 4);
      f32x4 pb2 = *reinterpret_cast<f32x4*>(p + 16 + t * 4);
#pragma unroll
      for (int r = 0; r < 4; ++r) {
        o[t][r] += pa[r];
        o2[t][r] += pb2[r];
      }
    }
    l_run += p[32];
    l_run2 += p[33];

    l_run += __shfl_xor(l_run, 16);
    l_run += __shfl_xor(l_run, 32);
    l_run2 += __shfl_xor(l_run2, 16);
    l_run2 += __shfl_xor(l_run2, 32);
    float inv = 1.f / l_run;
    float inv2 = 1.f / l_run2;
    int b = bh >> 2, h = bh & 3;
    bf16* orow = AO + ((size_t)b * NSEQ + (m0 + l15)) * CDIM + h * DH;
    bf16* orow2 = AO + ((size_t)b * NSEQ + (m0 + 16 + l15)) * CDIM + h * DH;
#pragma unroll
    for (int t = 0; t < 4; ++t) {
      short4v ov, ov2;
#pragma unroll
      for (int r = 0; r < 4; ++r) {
        ov[r] = f2b(o[t][r] * inv);
        ov2[r] = f2b(o2[t][r] * inv2);
      }
      *reinterpret_cast<short4v*>(orow + t * 16 + quad * 4) = ov;
      *reinterpret_cast<short4v*>(orow2 + t * 16 + quad * 4) = ov2;
    }
  }
}

// ---------------- Canonical 128-tile GEMM (r12-validated) ----------------
template <int KD, int EPI, int TI>
__global__ __launch_bounds__(256) void gemm128(const bf16* __restrict__ A, const bf16* __restrict__ Wm,
                                               const bf16* __restrict__ bias, const bf16* __restrict__ res,
                                               bf16* __restrict__ outp, int NC) {
  constexpr int KS = KD / 32;
  constexpr int AR = TI * 32;
  int tid = threadIdx.x;
  int wave = tid >> 6, lane = tid & 63;
  int l15 = lane & 15, quad = lane >> 4;
  int wm = (wave >> 1) * (TI * 16);
  int wn = (wave & 1) * 64;
  int m0 = blockIdx.x * AR;
  int n0 = blockIdx.y * 128;

  __shared__ __align__(16) bf16 abuf[2][AR * 40];
  __shared__ __align__(16) bf16 bbuf[2][128 * 40];

  int sr = tid >> 2, sc = (tid & 3) * 8;

  const bf16* ag[TI / 2];
#pragma unroll
  for (int u = 0; u < TI / 2; ++u) ag[u] = A + (size_t)(m0 + sr + u * 64) * KD + sc;
  const bf16* bg0 = Wm + (size_t)(n0 + sr) * KD + sc;
  const bf16* bg1 = Wm + (size_t)(n0 + 64 + sr) * KD + sc;

  f32x4 z = {0.f, 0.f, 0.f, 0.f};
  f32x4 acc[4][TI];
#pragma unroll
  for (int j = 0; j < 4; ++j)
#pragma unroll
    for (int i = 0; i < TI; ++i) acc[j][i] = z;

#pragma unroll
  for (int u = 0; u < TI / 2; ++u)
    *reinterpret_cast<short8*>(abuf[0] + (sr + u * 64) * 40 + sc) = ld8(ag[u]);
  *reinterpret_cast<short8*>(bbuf[0] + sr * 40 + sc) = ld8(bg0);
  *reinterpret_cast<short8*>(bbuf[0] + (64 + sr) * 40 + sc) = ld8(bg1);
  __syncthreads();

  for (int s = 0; s < KS; ++s) {
    int cur = s & 1;
    bool more = (s + 1 < KS);
    short8 anx[TI / 2], bnx0, bnx1;
    if (more) {
#pragma unroll
      for (int u = 0; u < TI / 2; ++u) anx[u] = ld8(ag[u] + (s + 1) * 32);
      bnx0 = ld8(bg0 + (s + 1) * 32);
      bnx1 = ld8(bg1 + (s + 1) * 32);
    }
    short8 af[TI], bf_[4];
#pragma unroll
    for (int i = 0; i < TI; ++i)
      af[i] = lds8(abuf[cur] + (size_t)(wm + i * 16 + l15) * 40 + quad * 8);
#pragma unroll
    for (int j = 0; j < 4; ++j)
      bf_[j] = lds8(bbuf[cur] + (size_t)(wn + j * 16 + l15) * 40 + quad * 8);
#pragma unroll
    for (int j = 0; j < 4; ++j)
#pragma unroll
      for (int i = 0; i < TI; ++i)
        acc[j][i] = mfma_bf16(bf_[j], af[i], acc[j][i]);
    if (more) {
#pragma unroll
      for (int u = 0; u < TI / 2; ++u)
        *reinterpret_cast<short8*>(abuf[1 - cur] + (sr + u * 64) * 40 + sc) = anx[u];
      *reinterpret_cast<short8*>(bbuf[1 - cur] + sr * 40 + sc) = bnx0;
      *reinterpret_cast<short8*>(bbuf[1 - cur] + (64 + sr) * 40 + sc) = bnx1;
    }
    __syncthreads();
  }

#pragma unroll
  for (int j = 0; j < 4; ++j) {
    int col0 = n0 + wn + j * 16 + quad * 4;
    float bb4[4];
    if (EPI != 0) {
      short4v bl = *reinterpret_cast<const short4v*>(bias + col0);
#pragma unroll
      for (int r = 0; r < 4; ++r) bb4[r] = b2f(bl[r]);
    }
#pragma unroll
    for (int i = 0; i < TI; ++i) {
      size_t idx = (size_t)(m0 + wm + i * 16 + l15) * NC + col0;
      short4v ov;
      if (EPI == 0) {
        short4v rl = *reinterpret_cast<const short4v*>(res + idx);
#pragma unroll
        for (int r = 0; r < 4; ++r) ov[r] = f2b(acc[j][i][r] + b2f(rl[r]));
      } else if (EPI == 1) {
#pragma unroll
        for (int r = 0; r < 4; ++r) {
          float hv = acc[j][i][r] + bb4[r];
          ov[r] = f2b(0.5f * hv * (1.f + erff(hv * 0.70710678118f)));
        }
      } else {
        short4v rl = *reinterpret_cast<const short4v*>(res + idx);
#pragma unroll
        for (int r = 0; r < 4; ++r) ov[r] = f2b(acc[j][i][r] + bb4[r] + b2f(rl[r]));
      }
      *reinterpret_cast<short4v*>(outp + idx) = ov;
    }
  }
}

// ---------------- LayerNorm bf16->bf16 ----------------
__global__ __launch_bounds__(256) void ln_kernel(const bf16* __restrict__ X, const bf16* __restrict__ g,
                                                 const bf16* __restrict__ bv, bf16* __restrict__ out) {
  int row = blockIdx.x * 4 + (threadIdx.x >> 6);
  int lane = threadIdx.x & 63;
  short4v raw = *reinterpret_cast<const short4v*>(X + (size_t)row * CDIM + lane * 4);
  float vv[4];
  float s = 0.f, sq = 0.f;
#pragma unroll
  for (int i = 0; i < 4; ++i) {
    float f = b2f(raw[i]);
    vv[i] = f; s += f; sq += f * f;
  }
#pragma unroll
  for (int off = 1; off < 64; off <<= 1) { s += __shfl_xor(s, off); sq += __shfl_xor(sq, off); }
  float mu = s * (1.f / CDIM);
  float var = sq * (1.f / CDIM) - mu * mu;
  float rstd = rsqrtf(var + 1e-5f);
#pragma unroll
  for (int i = 0; i < 4; ++i) {
    int c = lane * 4 + i;
    out[(size_t)row * CDIM + c] =
        __float2bfloat16((vv[i] - mu) * rstd * __bfloat162float(g[c]) + __bfloat162float(bv[c]));
  }
}

// ---------------- Final LayerNorm, flag-dependent dtype out ----------------
__global__ __launch_bounds__(256) void ln_out_kernel(const bf16* __restrict__ X, const bf16* __restrict__ g,
                                                     const bf16* __restrict__ bv, void* __restrict__ out,
                                                     const int* __restrict__ flag) {
  int is32 = flag[0];
  int row = blockIdx.x * 4 + (threadIdx.x >> 6);
  int lane = threadIdx.x & 63;
  short4v raw = *reinterpret_cast<const short4v*>(X + (size_t)row * CDIM + lane * 4);
  float vv[4];
  float s = 0.f, sq = 0.f;
#pragma unroll
  for (int i = 0; i < 4; ++i) {
    float f = b2f(raw[i]);
    vv[i] = f; s += f; sq += f * f;
  }
#pragma unroll
  for (int off = 1; off < 64; off <<= 1) { s += __shfl_xor(s, off); sq += __shfl_xor(sq, off); }
  float mu = s * (1.f / CDIM);
  float var = sq * (1.f / CDIM) - mu * mu;
  float rstd = rsqrtf(var + 1e-5f);
#pragma unroll
  for (int i = 0; i < 4; ++i) {
    int c = lane * 4 + i;
    size_t idx = (size_t)row * CDIM + c;
    float v = (vv[i] - mu) * rstd * __bfloat162float(g[c]) + __bfloat162float(bv[c]);
    if (is32) ((float*)out)[idx] = v;
    else      ((bf16*)out)[idx] = __float2bfloat16(v);
  }
}

extern "C" void kernel_launch(void* const* d_in, const int* in_sizes, int n_in,
                              void* d_out, int out_size, void* d_ws, size_t ws_size,
                              hipStream_t stream) {
  const int* Wp = (const int*)d_in[12];

  char* ws = (char*)d_ws;
  const size_t SZ = 4718592;  // 2304*4*256 bf16 bytes
  bf16* Qc  = (bf16*)(ws + 0 * SZ);
  bf16* Kc  = (bf16*)(ws + 1 * SZ);
  bf16* Vt  = (bf16*)(ws + 2 * SZ);
  bf16* AO  = (bf16*)(ws + 3 * SZ);
  bf16* F   = (bf16*)(ws + 4 * SZ);
  bf16* Y   = (bf16*)(ws + 5 * SZ);
  bf16* xc  = (bf16*)(ws + 6 * SZ);
  bf16* G   = (bf16*)(ws + 0);              // overlays Qc..AO (4*SZ exactly)
  bf16* Wqkvc  = (bf16*)(ws + 7 * SZ);
  bf16* Wprojc = (bf16*)(ws + 7 * SZ + 393216);
  bf16* W1c    = (bf16*)(ws + 7 * SZ + 524288);
  bf16* W2c    = (bf16*)(ws + 7 * SZ + 1048576);
  bf16* smallc = (bf16*)(ws + 7 * SZ + 1572864);
  bf16* g1c  = smallc + 0;
  bf16* b1c  = smallc + 256;
  bf16* g2c  = smallc + 512;
  bf16* b2c  = smallc + 768;
  bf16* bf1c = smallc + 1024;
  bf16* bf2c = smallc + 2048;
  int*  flagp = (int*)(ws + 7 * SZ + 1581568);
  bf16* outsc = (bf16*)d_out;

  detect_kernel<<<1, 256, 0, stream>>>(d_in[0], flagp);
  cvt_all_kernel<<<3073, 256, 0, stream>>>(d_in[0], d_in[1], d_in[2], d_in[7], d_in[9],
                                           d_in[3], d_in[4], d_in[5], d_in[6], d_in[8], d_in[10],
                                           xc, Wqkvc, Wprojc, W1c, W2c, smallc, flagp);

  qkv_kernel<<<dim3(36, 12), 256, 0, stream>>>(xc, Wqkvc, Qc, Kc, Vt, Wp);
  attn_kernel<<<dim3(16, 36), 256, 0, stream>>>(Qc, Kc, Vt, AO);
  gemm128<256, 0, 2><<<dim3(144, 2), 256, 0, stream>>>(AO, Wprojc, nullptr, xc, outsc, 256);
  ln_kernel<<<2304, 256, 0, stream>>>(outsc, g1c, b1c, F);
  gemm128<256, 1, 4><<<dim3(72, 8), 256, 0, stream>>>(F, W1c, bf1c, nullptr, G, 1024);
  gemm128<1024, 2, 2><<<dim3(144, 2), 256, 0, stream>>>(G, W2c, bf2c, F, Y, 256);
  ln_out_kernel<<<2304, 256, 0, stream>>>(Y, g2c, b2c, d_out, flagp);
}

// Round 4
// 207.687 us; speedup vs baseline: 1.2029x; 1.0227x over previous
//
#include <hip/hip_runtime.h>
#include <hip/hip_bf16.h>
#include <math.h>

typedef __hip_bfloat16 bf16;
typedef __attribute__((ext_vector_type(8))) short short8;
typedef __attribute__((ext_vector_type(4))) short short4v;
typedef __attribute__((ext_vector_type(4))) float f32x4;
typedef __attribute__((ext_vector_type(4))) unsigned int u32x4;

#define NSEQ 2304
#define CDIM 256
#define NHD  4
#define DH   64

#if __has_builtin(__builtin_amdgcn_exp2f)
#define EXP2F __builtin_amdgcn_exp2f
#else
#define EXP2F exp2f
#endif

static __device__ __forceinline__ f32x4 mfma_bf16(short8 a, short8 b, f32x4 c) {
  return __builtin_amdgcn_mfma_f32_16x16x32_bf16(a, b, c, 0, 0, 0);
}
static __device__ __forceinline__ short8 ld8(const bf16* p) {
  return *reinterpret_cast<const short8*>(p);
}
static __device__ __forceinline__ short8 lds8(const bf16* p) {
  return *reinterpret_cast<const short8*>(p);
}
static __device__ __forceinline__ float b2f(short v) {
  unsigned int u = ((unsigned int)(unsigned short)v) << 16;
  return __uint_as_float(u);
}
static __device__ __forceinline__ short f2b(float f) {
  bf16 h = __float2bfloat16(f);
  return *reinterpret_cast<short*>(&h);
}

// ---------------- dtype probe ----------------
__global__ __launch_bounds__(256) void detect_kernel(const void* __restrict__ xraw,
                                                     int* __restrict__ flag) {
  int t = threadIdx.x;
  const unsigned short* s = (const unsigned short*)xraw;
  int bad = 0;
#pragma unroll
  for (int i = 0; i < 8; ++i) {
    unsigned idx = (((unsigned)(t * 8 + i)) * 9173u) & ((1u << 20) - 1);
    unsigned short v = s[idx * 2];
    unsigned e = (v >> 7) & 0xFFu;
    if (e > 133u) bad++;
  }
  __shared__ int tot;
  if (t == 0) tot = 0;
  __syncthreads();
  atomicAdd(&tot, bad);
  __syncthreads();
  if (t == 0) flag[0] = (tot >= 16) ? 1 : 0;
}

// ---------------- fused conversion of all float inputs ----------------
__global__ __launch_bounds__(256) void cvt_all_kernel(const void* sx, const void* sqkv, const void* sproj,
                                                      const void* sw1, const void* sw2,
                                                      const void* g1, const void* b1, const void* g2,
                                                      const void* b2, const void* bias1, const void* bias2,
                                                      bf16* dx, bf16* dqkv, bf16* dproj,
                                                      bf16* dw1, bf16* dw2, bf16* dsm,
                                                      const int* __restrict__ flag) {
  int is32 = flag[0];
  int bid = blockIdx.x;
  const void* src; bf16* dst; int i4;
  if (bid < 2304)      { src = sx;    dst = dx;    i4 = bid * 256 + threadIdx.x; }
  else if (bid < 2496) { src = sqkv;  dst = dqkv;  i4 = (bid - 2304) * 256 + threadIdx.x; }
  else if (bid < 2560) { src = sproj; dst = dproj; i4 = (bid - 2496) * 256 + threadIdx.x; }
  else if (bid < 2816) { src = sw1;   dst = dw1;   i4 = (bid - 2560) * 256 + threadIdx.x; }
  else if (bid < 3072) { src = sw2;   dst = dw2;   i4 = (bid - 2816) * 256 + threadIdx.x; }
  else {
    const void* srcs[6] = {g1, b1, g2, b2, bias1, bias2};
    const int ns[6] = {256, 256, 256, 256, 1024, 256};
    const int off[6] = {0, 256, 512, 768, 1024, 2048};
    int t = threadIdx.x;
#pragma unroll
    for (int j = 0; j < 6; ++j)
      for (int i = t; i < ns[j]; i += 256) {
        if (is32) dsm[off[j] + i] = __float2bfloat16(((const float*)srcs[j])[i]);
        else      dsm[off[j] + i] = ((const bf16*)srcs[j])[i];
      }
    return;
  }
  if (is32) {
    float4 v = ((const float4*)src)[i4];
    short4v o;
    o[0] = f2b(v.x); o[1] = f2b(v.y); o[2] = f2b(v.z); o[3] = f2b(v.w);
    ((short4v*)dst)[i4] = o;
  } else {
    ((short4v*)dst)[i4] = ((const short4v*)src)[i4];
  }
}

// ---------------- QKV GEMM with FUSED RoPE epilogue (r13-validated) ----------------
__global__ __launch_bounds__(256, 1) void qkv_kernel(const bf16* __restrict__ X,
                                                     const bf16* __restrict__ Wqkv,
                                                     bf16* __restrict__ Q, bf16* __restrict__ K,
                                                     bf16* __restrict__ Vt,
                                                     const int* __restrict__ Wp) {
  int wave = threadIdx.x >> 6, lane = threadIdx.x & 63;
  int l15 = lane & 15, quad = lane >> 4;
  int m0 = (blockIdx.x * 4 + wave) * 64;
  int n0 = blockIdx.y * 64;
  const bf16* arow = X + (size_t)(m0 + l15) * CDIM + quad * 8;
  const bf16* brow = Wqkv + (size_t)(n0 + l15) * CDIM + quad * 8;
  f32x4 z = {0.f, 0.f, 0.f, 0.f};
  f32x4 acc[4][4];
#pragma unroll
  for (int j = 0; j < 4; ++j)
#pragma unroll
    for (int i = 0; i < 4; ++i) acc[j][i] = z;

  short8 a[4], b[4];
#pragma unroll
  for (int i = 0; i < 4; ++i) a[i] = ld8(arow + (size_t)i * 16 * CDIM);
#pragma unroll
  for (int j = 0; j < 4; ++j) b[j] = ld8(brow + (size_t)j * 16 * CDIM);
#pragma unroll
  for (int kk = 32; kk <= CDIM; kk += 32) {
    short8 an[4], bn[4];
    if (kk < CDIM) {
#pragma unroll
      for (int i = 0; i < 4; ++i) an[i] = ld8(arow + (size_t)i * 16 * CDIM + kk);
#pragma unroll
      for (int j = 0; j < 4; ++j) bn[j] = ld8(brow + (size_t)j * 16 * CDIM + kk);
    }
#pragma unroll
    for (int j = 0; j < 4; ++j)
#pragma unroll
      for (int i = 0; i < 4; ++i) acc[j][i] = mfma_bf16(b[j], a[i], acc[j][i]);
    if (kk < CDIM) {
#pragma unroll
      for (int i = 0; i < 4; ++i) a[i] = an[i];
#pragma unroll
      for (int j = 0; j < 4; ++j) b[j] = bn[j];
    }
  }

  int which = n0 >> 8, h = (n0 & 255) >> 6;
  if (which == 2) {
#pragma unroll
    for (int j = 0; j < 4; ++j) {
      int d0 = j * 16 + quad * 4;
#pragma unroll
      for (int i = 0; i < 4; ++i) {
        int gm = m0 + i * 16 + l15;
        int bb = gm / NSEQ, n = gm % NSEQ;
        int bh = bb * NHD + h;
#pragma unroll
        for (int r = 0; r < 4; ++r)
          Vt[((size_t)bh * DH + d0 + r) * NSEQ + n] = __float2bfloat16(acc[j][i][r]);
      }
    }
  } else {
    int Wv = Wp[0];
    if (Wv <= 0 || Wv > 65536) Wv = 48;
    bf16* dst = (which == 0) ? Q : K;
    const float cc = -0.28782313662425574f;  // -ln(10000)/32
    const float EC1 = 0.7498942434f, EC2 = 0.5623413252f, EC3 = 0.4216965034f;
#pragma unroll
    for (int i = 0; i < 4; ++i) {
      int gm = m0 + i * 16 + l15;
      int bb = gm / NSEQ, n = gm % NSEQ;
      int bh = bb * NHD + h;
      int py = n / Wv, px = n - py * Wv;
#pragma unroll
      for (int j = 0; j < 4; ++j) {
        int d0 = j * 16 + quad * 4;
        float pos = (d0 & 32) ? (float)px : (float)py;
        int base = d0 & 31;
        float fb = __expf(cc * (float)base);
        float f0 = fb, f1 = fb * EC1, f2 = fb * EC2, f3 = fb * EC3;
        float s0, c0, s1, c1, s2, c2, s3, c3;
        __sincosf(pos * f0, &s0, &c0);
        __sincosf(pos * f1, &s1, &c1);
        __sincosf(pos * f2, &s2, &c2);
        __sincosf(pos * f3, &s3, &c3);
        float a0 = acc[j][i][0], a1 = acc[j][i][1], a2 = acc[j][i][2], a3 = acc[j][i][3];
        short4v ov;
        ov[0] = f2b(a0 * c0 - a1 * s0);
        ov[1] = f2b(a1 * c1 + a0 * s1);
        ov[2] = f2b(a2 * c2 - a3 * s2);
        ov[3] = f2b(a3 * c3 + a2 * s3);
        *reinterpret_cast<short4v*>(dst + ((size_t)bh * NSEQ + n) * DH + d0) = ov;
      }
    }
  }
}

// ---------------- Flash attention ----------------
// r3 K-split structure, with the P LDS round-trip replaced by in-register
// redistribution: QK leaves lane(l15,quad) holding P(q=l15, k=16kt+4quad+r);
// the PV B-frag needs P(q=l15, k=8quad+j). cvt_pk pairs into u32s then
// permlane32_swap + permlane16_swap produce exactly the B-frag registers
// (derivation: after the two exchanges, reg0 = {A0q0,A0q2,A1q0,A1q2} etc.,
// i.e. lane quad T holds k=8T..8T+7). Removes plds (10.2KB), 16KB/block-iter
// of LDS traffic, and the ds_write->lgkmcnt->ds_read latency link.
__global__ __launch_bounds__(256, 4) void attn_kernel(const bf16* __restrict__ Q, const bf16* __restrict__ K,
                                                      const bf16* __restrict__ Vt, bf16* __restrict__ AO) {
  int bh = blockIdx.x, qt = blockIdx.y;
  int tid = threadIdx.x;
  int wave = tid >> 6, lane = tid & 63;
  int l15 = lane & 15, quad = lane >> 4;
  int qf = wave & 1;   // q half: rows [qf*32, qf*32+32)
  int ks = wave >> 1;  // k slice: cols [ks*32, ks*32+32) of each 64-tile
  int m0 = qt * 64 + qf * 32;
  const bf16* Qb = Q + (size_t)bh * NSEQ * DH;
  const bf16* Kb = K + (size_t)bh * NSEQ * DH;
  const bf16* Vb = Vt + (size_t)bh * DH * NSEQ;

  __shared__ __align__(16) bf16 kbuf[2][64 * 72];
  __shared__ __align__(16) bf16 vbuf[2][64 * 72];

  // staging: 256 threads cover 512 short8 slots per tile (2 K + 2 V each)
  int r1 = tid >> 3, c1 = (tid & 7) * 8;
  int r1b = r1 + 32;

  // Q pre-scaled by 0.125 * log2(e) so p = exp2(s) directly
  const float QS = 0.18033688011112042f;
  short8 qa0 = ld8(Qb + (size_t)(m0 + l15) * DH + quad * 8);
  short8 qa1 = ld8(Qb + (size_t)(m0 + l15) * DH + 32 + quad * 8);
  short8 qb0 = ld8(Qb + (size_t)(m0 + 16 + l15) * DH + quad * 8);
  short8 qb1 = ld8(Qb + (size_t)(m0 + 16 + l15) * DH + 32 + quad * 8);
#pragma unroll
  for (int i = 0; i < 8; ++i) {
    qa0[i] = f2b(b2f(qa0[i]) * QS);
    qa1[i] = f2b(b2f(qa1[i]) * QS);
    qb0[i] = f2b(b2f(qb0[i]) * QS);
    qb1[i] = f2b(b2f(qb1[i]) * QS);
  }

  f32x4 z = {0.f, 0.f, 0.f, 0.f};
  f32x4 o[4] = {z, z, z, z};
  f32x4 o2[4] = {z, z, z, z};
  float l_run = 0.f, l_run2 = 0.f;

  // stage K/V tile 0
  *reinterpret_cast<short8*>(kbuf[0] + r1 * 72 + c1)  = ld8(Kb + (size_t)r1 * DH + c1);
  *reinterpret_cast<short8*>(kbuf[0] + r1b * 72 + c1) = ld8(Kb + (size_t)r1b * DH + c1);
  *reinterpret_cast<short8*>(vbuf[0] + r1 * 72 + c1)  = ld8(Vb + (size_t)r1 * NSEQ + c1);
  *reinterpret_cast<short8*>(vbuf[0] + r1b * 72 + c1) = ld8(Vb + (size_t)r1b * NSEQ + c1);
  __syncthreads();

  for (int it = 0; it < NSEQ / 64; ++it) {
    int cur = it & 1;
    bool more = (it + 1 < NSEQ / 64);

    // prefetch next K/V tile into registers (global)
    short8 kpA, kpB, vpA, vpB;
    if (more) {
      int kn = (it + 1) * 64;
      kpA = ld8(Kb + (size_t)(kn + r1) * DH + c1);
      kpB = ld8(Kb + (size_t)(kn + r1b) * DH + c1);
      vpA = ld8(Vb + (size_t)r1 * NSEQ + kn + c1);
      vpB = ld8(Vb + (size_t)r1b * NSEQ + kn + c1);
    }

    const bf16* kb = kbuf[cur];
    const bf16* vb = vbuf[cur];

    // QK^T for this wave's 32 k-rows x 32 q-rows
    f32x4 s[2], s2[2];
#pragma unroll
    for (int kt = 0; kt < 2; ++kt) {
      const bf16* kp = kb + (size_t)(ks * 32 + kt * 16 + l15) * 72 + quad * 8;
      short8 kf0 = lds8(kp);
      short8 kf1 = lds8(kp + 32);
      s[kt] = mfma_bf16(kf0, qa0, z);
      s[kt] = mfma_bf16(kf1, qa1, s[kt]);
      s2[kt] = mfma_bf16(kf0, qb0, z);
      s2[kt] = mfma_bf16(kf1, qb1, s2[kt]);
    }

    // exp2 + in-register P->B-frag redistribution (no LDS)
    unsigned int A0, B0, A1, B1, C0, D0, C1, D1;
    {
      float p00 = EXP2F(s[0][0]), p01 = EXP2F(s[0][1]), p02 = EXP2F(s[0][2]), p03 = EXP2F(s[0][3]);
      float p10 = EXP2F(s[1][0]), p11 = EXP2F(s[1][1]), p12 = EXP2F(s[1][2]), p13 = EXP2F(s[1][3]);
      l_run += ((p00 + p01) + (p02 + p03)) + ((p10 + p11) + (p12 + p13));
      asm("v_cvt_pk_bf16_f32 %0, %1, %2" : "=v"(A0) : "v"(p00), "v"(p01));
      asm("v_cvt_pk_bf16_f32 %0, %1, %2" : "=v"(B0) : "v"(p02), "v"(p03));
      asm("v_cvt_pk_bf16_f32 %0, %1, %2" : "=v"(A1) : "v"(p10), "v"(p11));
      asm("v_cvt_pk_bf16_f32 %0, %1, %2" : "=v"(B1) : "v"(p12), "v"(p13));
      float q00 = EXP2F(s2[0][0]), q01 = EXP2F(s2[0][1]), q02 = EXP2F(s2[0][2]), q03 = EXP2F(s2[0][3]);
      float q10 = EXP2F(s2[1][0]), q11 = EXP2F(s2[1][1]), q12 = EXP2F(s2[1][2]), q13 = EXP2F(s2[1][3]);
      l_run2 += ((q00 + q01) + (q02 + q03)) + ((q10 + q11) + (q12 + q13));
      asm("v_cvt_pk_bf16_f32 %0, %1, %2" : "=v"(C0) : "v"(q00), "v"(q01));
      asm("v_cvt_pk_bf16_f32 %0, %1, %2" : "=v"(D0) : "v"(q02), "v"(q03));
      asm("v_cvt_pk_bf16_f32 %0, %1, %2" : "=v"(C1) : "v"(q10), "v"(q11));
      asm("v_cvt_pk_bf16_f32 %0, %1, %2" : "=v"(D1) : "v"(q12), "v"(q13));
    }
    asm("v_permlane32_swap_b32 %0, %1" : "+v"(A0), "+v"(A1));
    asm("v_permlane16_swap_b32 %0, %1" : "+v"(A0), "+v"(A1));
    asm("v_permlane32_swap_b32 %0, %1" : "+v"(B0), "+v"(B1));
    asm("v_permlane16_swap_b32 %0, %1" : "+v"(B0), "+v"(B1));
    asm("v_permlane32_swap_b32 %0, %1" : "+v"(C0), "+v"(C1));
    asm("v_permlane16_swap_b32 %0, %1" : "+v"(C0), "+v"(C1));
    asm("v_permlane32_swap_b32 %0, %1" : "+v"(D0), "+v"(D1));
    asm("v_permlane16_swap_b32 %0, %1" : "+v"(D0), "+v"(D1));

    u32x4 wA; wA[0] = A0; wA[1] = B0; wA[2] = A1; wA[3] = B1;
    u32x4 wB; wB[0] = C0; wB[1] = D0; wB[2] = C1; wB[3] = D1;
    short8 pfA = *reinterpret_cast<short8*>(&wA);
    short8 pfB = *reinterpret_cast<short8*>(&wB);

    // PV for this wave's 32 k-cols (partial o over the k-slice)
#pragma unroll
    for (int t = 0; t < 4; ++t) {
      short8 vf = lds8(vb + (size_t)(t * 16 + l15) * 72 + ks * 32 + quad * 8);
      o[t] = mfma_bf16(vf, pfA, o[t]);
      o2[t] = mfma_bf16(vf, pfB, o2[t]);
    }

    if (more) {
      bf16* kn_ = kbuf[1 - cur];
      bf16* vn_ = vbuf[1 - cur];
      *reinterpret_cast<short8*>(kn_ + r1 * 72 + c1)  = kpA;
      *reinterpret_cast<short8*>(kn_ + r1b * 72 + c1) = kpB;
      *reinterpret_cast<short8*>(vn_ + r1 * 72 + c1)  = vpA;
      *reinterpret_cast<short8*>(vn_ + r1b * 72 + c1) = vpB;
    }
    __syncthreads();
  }

  // ---- cross-kslice combine via LDS scratch (kbuf is dead now) ----
  float* scr = (float*)kbuf;
  int slot = qf * 64 + lane;  // wave2 pairs wave0 (qf=0), wave3 pairs wave1
  if (ks == 1) {
    float* p = scr + slot * 36;
#pragma unroll
    for (int t = 0; t < 4; ++t) {
      *reinterpret_cast<f32x4*>(p + t * 4) = o[t];
      *reinterpret_cast<f32x4*>(p + 16 + t * 4) = o2[t];
    }
    p[32] = l_run;
    p[33] = l_run2;
  }
  __syncthreads();
  if (ks == 0) {
    float* p = scr + slot * 36;
#pragma unroll
    for (int t = 0; t < 4; ++t) {
      f32x4 pa = *reinterpret_cast<f32x4*>(p + t * 4);
      f32x4 pb2 = *reinterpret_cast<f32x4*>(p + 16 + t * 4);
#pragma unroll
      for (int r = 0; r < 4; ++r) {
        o[t][r] += pa[r];
        o2[t][r] += pb2[r];
      }
    }
    l_run += p[32];
    l_run2 += p[33];

    l_run += __shfl_xor(l_run, 16);
    l_run += __shfl_xor(l_run, 32);
    l_run2 += __shfl_xor(l_run2, 16);
    l_run2 += __shfl_xor(l_run2, 32);
    float inv = 1.f / l_run;
    float inv2 = 1.f / l_run2;
    int b = bh >> 2, h = bh & 3;
    bf16* orow = AO + ((size_t)b * NSEQ + (m0 + l15)) * CDIM + h * DH;
    bf16* orow2 = AO + ((size_t)b * NSEQ + (m0 + 16 + l15)) * CDIM + h * DH;
#pragma unroll
    for (int t = 0; t < 4; ++t) {
      short4v ov, ov2;
#pragma unroll
      for (int r = 0; r < 4; ++r) {
        ov[r] = f2b(o[t][r] * inv);
        ov2[r] = f2b(o2[t][r] * inv2);
      }
      *reinterpret_cast<short4v*>(orow + t * 16 + quad * 4) = ov;
      *reinterpret_cast<short4v*>(orow2 + t * 16 + quad * 4) = ov2;
    }
  }
}

// ---------------- Canonical 128-tile GEMM (r12-validated) ----------------
template <int KD, int EPI, int TI>
__global__ __launch_bounds__(256) void gemm128(const bf16* __restrict__ A, const bf16* __restrict__ Wm,
                                               const bf16* __restrict__ bias, const bf16* __restrict__ res,
                                               bf16* __restrict__ outp, int NC) {
  constexpr int KS = KD / 32;
  constexpr int AR = TI * 32;
  int tid = threadIdx.x;
  int wave = tid >> 6, lane = tid & 63;
  int l15 = lane & 15, quad = lane >> 4;
  int wm = (wave >> 1) * (TI * 16);
  int wn = (wave & 1) * 64;
  int m0 = blockIdx.x * AR;
  int n0 = blockIdx.y * 128;

  __shared__ __align__(16) bf16 abuf[2][AR * 40];
  __shared__ __align__(16) bf16 bbuf[2][128 * 40];

  int sr = tid >> 2, sc = (tid & 3) * 8;

  const bf16* ag[TI / 2];
#pragma unroll
  for (int u = 0; u < TI / 2; ++u) ag[u] = A + (size_t)(m0 + sr + u * 64) * KD + sc;
  const bf16* bg0 = Wm + (size_t)(n0 + sr) * KD + sc;
  const bf16* bg1 = Wm + (size_t)(n0 + 64 + sr) * KD + sc;

  f32x4 z = {0.f, 0.f, 0.f, 0.f};
  f32x4 acc[4][TI];
#pragma unroll
  for (int j = 0; j < 4; ++j)
#pragma unroll
    for (int i = 0; i < TI; ++i) acc[j][i] = z;

#pragma unroll
  for (int u = 0; u < TI / 2; ++u)
    *reinterpret_cast<short8*>(abuf[0] + (sr + u * 64) * 40 + sc) = ld8(ag[u]);
  *reinterpret_cast<short8*>(bbuf[0] + sr * 40 + sc) = ld8(bg0);
  *reinterpret_cast<short8*>(bbuf[0] + (64 + sr) * 40 + sc) = ld8(bg1);
  __syncthreads();

  for (int s = 0; s < KS; ++s) {
    int cur = s & 1;
    bool more = (s + 1 < KS);
    short8 anx[TI / 2], bnx0, bnx1;
    if (more) {
#pragma unroll
      for (int u = 0; u < TI / 2; ++u) anx[u] = ld8(ag[u] + (s + 1) * 32);
      bnx0 = ld8(bg0 + (s + 1) * 32);
      bnx1 = ld8(bg1 + (s + 1) * 32);
    }
    short8 af[TI], bf_[4];
#pragma unroll
    for (int i = 0; i < TI; ++i)
      af[i] = lds8(abuf[cur] + (size_t)(wm + i * 16 + l15) * 40 + quad * 8);
#pragma unroll
    for (int j = 0; j < 4; ++j)
      bf_[j] = lds8(bbuf[cur] + (size_t)(wn + j * 16 + l15) * 40 + quad * 8);
#pragma unroll
    for (int j = 0; j < 4; ++j)
#pragma unroll
      for (int i = 0; i < TI; ++i)
        acc[j][i] = mfma_bf16(bf_[j], af[i], acc[j][i]);
    if (more) {
#pragma unroll
      for (int u = 0; u < TI / 2; ++u)
        *reinterpret_cast<short8*>(abuf[1 - cur] + (sr + u * 64) * 40 + sc) = anx[u];
      *reinterpret_cast<short8*>(bbuf[1 - cur] + sr * 40 + sc) = bnx0;
      *reinterpret_cast<short8*>(bbuf[1 - cur] + (64 + sr) * 40 + sc) = bnx1;
    }
    __syncthreads();
  }

#pragma unroll
  for (int j = 0; j < 4; ++j) {
    int col0 = n0 + wn + j * 16 + quad * 4;
    float bb4[4];
    if (EPI != 0) {
      short4v bl = *reinterpret_cast<const short4v*>(bias + col0);
#pragma unroll
      for (int r = 0; r < 4; ++r) bb4[r] = b2f(bl[r]);
    }
#pragma unroll
    for (int i = 0; i < TI; ++i) {
      size_t idx = (size_t)(m0 + wm + i * 16 + l15) * NC + col0;
      short4v ov;
      if (EPI == 0) {
        short4v rl = *reinterpret_cast<const short4v*>(res + idx);
#pragma unroll
        for (int r = 0; r < 4; ++r) ov[r] = f2b(acc[j][i][r] + b2f(rl[r]));
      } else if (EPI == 1) {
#pragma unroll
        for (int r = 0; r < 4; ++r) {
          float hv = acc[j][i][r] + bb4[r];
          ov[r] = f2b(0.5f * hv * (1.f + erff(hv * 0.70710678118f)));
        }
      } else {
        short4v rl = *reinterpret_cast<const short4v*>(res + idx);
#pragma unroll
        for (int r = 0; r < 4; ++r) ov[r] = f2b(acc[j][i][r] + bb4[r] + b2f(rl[r]));
      }
      *reinterpret_cast<short4v*>(outp + idx) = ov;
    }
  }
}

// ---------------- LayerNorm bf16->bf16 ----------------
__global__ __launch_bounds__(256) void ln_kernel(const bf16* __restrict__ X, const bf16* __restrict__ g,
                                                 const bf16* __restrict__ bv, bf16* __restrict__ out) {
  int row = blockIdx.x * 4 + (threadIdx.x >> 6);
  int lane = threadIdx.x & 63;
  short4v raw = *reinterpret_cast<const short4v*>(X + (size_t)row * CDIM + lane * 4);
  float vv[4];
  float s = 0.f, sq = 0.f;
#pragma unroll
  for (int i = 0; i < 4; ++i) {
    float f = b2f(raw[i]);
    vv[i] = f; s += f; sq += f * f;
  }
#pragma unroll
  for (int off = 1; off < 64; off <<= 1) { s += __shfl_xor(s, off); sq += __shfl_xor(sq, off); }
  float mu = s * (1.f / CDIM);
  float var = sq * (1.f / CDIM) - mu * mu;
  float rstd = rsqrtf(var + 1e-5f);
#pragma unroll
  for (int i = 0; i < 4; ++i) {
    int c = lane * 4 + i;
    out[(size_t)row * CDIM + c] =
        __float2bfloat16((vv[i] - mu) * rstd * __bfloat162float(g[c]) + __bfloat162float(bv[c]));
  }
}

// ---------------- Final LayerNorm, flag-dependent dtype out ----------------
__global__ __launch_bounds__(256) void ln_out_kernel(const bf16* __restrict__ X, const bf16* __restrict__ g,
                                                     const bf16* __restrict__ bv, void* __restrict__ out,
                                                     const int* __restrict__ flag) {
  int is32 = flag[0];
  int row = blockIdx.x * 4 + (threadIdx.x >> 6);
  int lane = threadIdx.x & 63;
  short4v raw = *reinterpret_cast<const short4v*>(X + (size_t)row * CDIM + lane * 4);
  float vv[4];
  float s = 0.f, sq = 0.f;
#pragma unroll
  for (int i = 0; i < 4; ++i) {
    float f = b2f(raw[i]);
    vv[i] = f; s += f; sq += f * f;
  }
#pragma unroll
  for (int off = 1; off < 64; off <<= 1) { s += __shfl_xor(s, off); sq += __shfl_xor(sq, off); }
  float mu = s * (1.f / CDIM);
  float var = sq * (1.f / CDIM) - mu * mu;
  float rstd = rsqrtf(var + 1e-5f);
#pragma unroll
  for (int i = 0; i < 4; ++i) {
    int c = lane * 4 + i;
    size_t idx = (size_t)row * CDIM + c;
    float v = (vv[i] - mu) * rstd * __bfloat162float(g[c]) + __bfloat162float(bv[c]);
    if (is32) ((float*)out)[idx] = v;
    else      ((bf16*)out)[idx] = __float2bfloat16(v);
  }
}

extern "C" void kernel_launch(void* const* d_in, const int* in_sizes, int n_in,
                              void* d_out, int out_size, void* d_ws, size_t ws_size,
                              hipStream_t stream) {
  const int* Wp = (const int*)d_in[12];

  char* ws = (char*)d_ws;
  const size_t SZ = 4718592;  // 2304*4*256 bf16 bytes
  bf16* Qc  = (bf16*)(ws + 0 * SZ);
  bf16* Kc  = (bf16*)(ws + 1 * SZ);
  bf16* Vt  = (bf16*)(ws + 2 * SZ);
  bf16* AO  = (bf16*)(ws + 3 * SZ);
  bf16* F   = (bf16*)(ws + 4 * SZ);
  bf16* Y   = (bf16*)(ws + 5 * SZ);
  bf16* xc  = (bf16*)(ws + 6 * SZ);
  bf16* G   = (bf16*)(ws + 0);              // overlays Qc..AO (4*SZ exactly)
  bf16* Wqkvc  = (bf16*)(ws + 7 * SZ);
  bf16* Wprojc = (bf16*)(ws + 7 * SZ + 393216);
  bf16* W1c    = (bf16*)(ws + 7 * SZ + 524288);
  bf16* W2c    = (bf16*)(ws + 7 * SZ + 1048576);
  bf16* smallc = (bf16*)(ws + 7 * SZ + 1572864);
  bf16* g1c  = smallc + 0;
  bf16* b1c  = smallc + 256;
  bf16* g2c  = smallc + 512;
  bf16* b2c  = smallc + 768;
  bf16* bf1c = smallc + 1024;
  bf16* bf2c = smallc + 2048;
  int*  flagp = (int*)(ws + 7 * SZ + 1581568);
  bf16* outsc = (bf16*)d_out;

  detect_kernel<<<1, 256, 0, stream>>>(d_in[0], flagp);
  cvt_all_kernel<<<3073, 256, 0, stream>>>(d_in[0], d_in[1], d_in[2], d_in[7], d_in[9],
                                           d_in[3], d_in[4], d_in[5], d_in[6], d_in[8], d_in[10],
                                           xc, Wqkvc, Wprojc, W1c, W2c, smallc, flagp);

  qkv_kernel<<<dim3(36, 12), 256, 0, stream>>>(xc, Wqkvc, Qc, Kc, Vt, Wp);
  attn_kernel<<<dim3(16, 36), 256, 0, stream>>>(Qc, Kc, Vt, AO);
  gemm128<256, 0, 2><<<dim3(144, 2), 256, 0, stream>>>(AO, Wprojc, nullptr, xc, outsc, 256);
  ln_kernel<<<2304, 256, 0, stream>>>(outsc, g1c, b1c, F);
  gemm128<256, 1, 4><<<dim3(72, 8), 256, 0, stream>>>(F, W1c, bf1c, nullptr, G, 1024);
  gemm128<1024, 2, 2><<<dim3(144, 2), 256, 0, stream>>>(G, W2c, bf2c, F, Y, 256);
  ln_out_kernel<<<2304, 256, 0, stream>>>(Y, g2c, b2c, d_out, flagp);
}

// Round 5
// 205.303 us; speedup vs baseline: 1.2168x; 1.0116x over previous
//
#include <hip/hip_runtime.h>
#include <hip/hip_bf16.h>
#include <math.h>

typedef __hip_bfloat16 bf16;
typedef __attribute__((ext_vector_type(8))) short short8;
typedef __attribute__((ext_vector_type(4))) short short4v;
typedef __attribute__((ext_vector_type(4))) float f32x4;
typedef __attribute__((ext_vector_type(4))) unsigned int u32x4;

#define NSEQ 2304
#define CDIM 256
#define NHD  4
#define DH   64

#if __has_builtin(__builtin_amdgcn_exp2f)
#define EXP2F __builtin_amdgcn_exp2f
#else
#define EXP2F exp2f
#endif

static __device__ __forceinline__ f32x4 mfma_bf16(short8 a, short8 b, f32x4 c) {
  return __builtin_amdgcn_mfma_f32_16x16x32_bf16(a, b, c, 0, 0, 0);
}
static __device__ __forceinline__ short8 ld8(const bf16* p) {
  return *reinterpret_cast<const short8*>(p);
}
static __device__ __forceinline__ short8 lds8(const bf16* p) {
  return *reinterpret_cast<const short8*>(p);
}
static __device__ __forceinline__ float b2f(short v) {
  unsigned int u = ((unsigned int)(unsigned short)v) << 16;
  return __uint_as_float(u);
}
static __device__ __forceinline__ short f2b(float f) {
  bf16 h = __float2bfloat16(f);
  return *reinterpret_cast<short*>(&h);
}

// ---------------- dtype probe ----------------
__global__ __launch_bounds__(256) void detect_kernel(const void* __restrict__ xraw,
                                                     int* __restrict__ flag) {
  int t = threadIdx.x;
  const unsigned short* s = (const unsigned short*)xraw;
  int bad = 0;
#pragma unroll
  for (int i = 0; i < 8; ++i) {
    unsigned idx = (((unsigned)(t * 8 + i)) * 9173u) & ((1u << 20) - 1);
    unsigned short v = s[idx * 2];
    unsigned e = (v >> 7) & 0xFFu;
    if (e > 133u) bad++;
  }
  __shared__ int tot;
  if (t == 0) tot = 0;
  __syncthreads();
  atomicAdd(&tot, bad);
  __syncthreads();
  if (t == 0) flag[0] = (tot >= 16) ? 1 : 0;
}

// ---------------- fused conversion of all float inputs ----------------
__global__ __launch_bounds__(256) void cvt_all_kernel(const void* sx, const void* sqkv, const void* sproj,
                                                      const void* sw1, const void* sw2,
                                                      const void* g1, const void* b1, const void* g2,
                                                      const void* b2, const void* bias1, const void* bias2,
                                                      bf16* dx, bf16* dqkv, bf16* dproj,
                                                      bf16* dw1, bf16* dw2, bf16* dsm,
                                                      const int* __restrict__ flag) {
  int is32 = flag[0];
  int bid = blockIdx.x;
  const void* src; bf16* dst; int i4;
  if (bid < 2304)      { src = sx;    dst = dx;    i4 = bid * 256 + threadIdx.x; }
  else if (bid < 2496) { src = sqkv;  dst = dqkv;  i4 = (bid - 2304) * 256 + threadIdx.x; }
  else if (bid < 2560) { src = sproj; dst = dproj; i4 = (bid - 2496) * 256 + threadIdx.x; }
  else if (bid < 2816) { src = sw1;   dst = dw1;   i4 = (bid - 2560) * 256 + threadIdx.x; }
  else if (bid < 3072) { src = sw2;   dst = dw2;   i4 = (bid - 2816) * 256 + threadIdx.x; }
  else {
    const void* srcs[6] = {g1, b1, g2, b2, bias1, bias2};
    const int ns[6] = {256, 256, 256, 256, 1024, 256};
    const int off[6] = {0, 256, 512, 768, 1024, 2048};
    int t = threadIdx.x;
#pragma unroll
    for (int j = 0; j < 6; ++j)
      for (int i = t; i < ns[j]; i += 256) {
        if (is32) dsm[off[j] + i] = __float2bfloat16(((const float*)srcs[j])[i]);
        else      dsm[off[j] + i] = ((const bf16*)srcs[j])[i];
      }
    return;
  }
  if (is32) {
    float4 v = ((const float4*)src)[i4];
    short4v o;
    o[0] = f2b(v.x); o[1] = f2b(v.y); o[2] = f2b(v.z); o[3] = f2b(v.w);
    ((short4v*)dst)[i4] = o;
  } else {
    ((short4v*)dst)[i4] = ((const short4v*)src)[i4];
  }
}

// ---------------- QKV GEMM with FUSED RoPE epilogue (r13-validated) ----------------
__global__ __launch_bounds__(256, 1) void qkv_kernel(const bf16* __restrict__ X,
                                                     const bf16* __restrict__ Wqkv,
                                                     bf16* __restrict__ Q, bf16* __restrict__ K,
                                                     bf16* __restrict__ Vt,
                                                     const int* __restrict__ Wp) {
  int wave = threadIdx.x >> 6, lane = threadIdx.x & 63;
  int l15 = lane & 15, quad = lane >> 4;
  int m0 = (blockIdx.x * 4 + wave) * 64;
  int n0 = blockIdx.y * 64;
  const bf16* arow = X + (size_t)(m0 + l15) * CDIM + quad * 8;
  const bf16* brow = Wqkv + (size_t)(n0 + l15) * CDIM + quad * 8;
  f32x4 z = {0.f, 0.f, 0.f, 0.f};
  f32x4 acc[4][4];
#pragma unroll
  for (int j = 0; j < 4; ++j)
#pragma unroll
    for (int i = 0; i < 4; ++i) acc[j][i] = z;

  short8 a[4], b[4];
#pragma unroll
  for (int i = 0; i < 4; ++i) a[i] = ld8(arow + (size_t)i * 16 * CDIM);
#pragma unroll
  for (int j = 0; j < 4; ++j) b[j] = ld8(brow + (size_t)j * 16 * CDIM);
#pragma unroll
  for (int kk = 32; kk <= CDIM; kk += 32) {
    short8 an[4], bn[4];
    if (kk < CDIM) {
#pragma unroll
      for (int i = 0; i < 4; ++i) an[i] = ld8(arow + (size_t)i * 16 * CDIM + kk);
#pragma unroll
      for (int j = 0; j < 4; ++j) bn[j] = ld8(brow + (size_t)j * 16 * CDIM + kk);
    }
#pragma unroll
    for (int j = 0; j < 4; ++j)
#pragma unroll
      for (int i = 0; i < 4; ++i) acc[j][i] = mfma_bf16(b[j], a[i], acc[j][i]);
    if (kk < CDIM) {
#pragma unroll
      for (int i = 0; i < 4; ++i) a[i] = an[i];
#pragma unroll
      for (int j = 0; j < 4; ++j) b[j] = bn[j];
    }
  }

  int which = n0 >> 8, h = (n0 & 255) >> 6;
  if (which == 2) {
#pragma unroll
    for (int j = 0; j < 4; ++j) {
      int d0 = j * 16 + quad * 4;
#pragma unroll
      for (int i = 0; i < 4; ++i) {
        int gm = m0 + i * 16 + l15;
        int bb = gm / NSEQ, n = gm % NSEQ;
        int bh = bb * NHD + h;
#pragma unroll
        for (int r = 0; r < 4; ++r)
          Vt[((size_t)bh * DH + d0 + r) * NSEQ + n] = __float2bfloat16(acc[j][i][r]);
      }
    }
  } else {
    int Wv = Wp[0];
    if (Wv <= 0 || Wv > 65536) Wv = 48;
    bf16* dst = (which == 0) ? Q : K;
    const float cc = -0.28782313662425574f;  // -ln(10000)/32
    const float EC1 = 0.7498942434f, EC2 = 0.5623413252f, EC3 = 0.4216965034f;
#pragma unroll
    for (int i = 0; i < 4; ++i) {
      int gm = m0 + i * 16 + l15;
      int bb = gm / NSEQ, n = gm % NSEQ;
      int bh = bb * NHD + h;
      int py = n / Wv, px = n - py * Wv;
#pragma unroll
      for (int j = 0; j < 4; ++j) {
        int d0 = j * 16 + quad * 4;
        float pos = (d0 & 32) ? (float)px : (float)py;
        int base = d0 & 31;
        float fb = __expf(cc * (float)base);
        float f0 = fb, f1 = fb * EC1, f2 = fb * EC2, f3 = fb * EC3;
        float s0, c0, s1, c1, s2, c2, s3, c3;
        __sincosf(pos * f0, &s0, &c0);
        __sincosf(pos * f1, &s1, &c1);
        __sincosf(pos * f2, &s2, &c2);
        __sincosf(pos * f3, &s3, &c3);
        float a0 = acc[j][i][0], a1 = acc[j][i][1], a2 = acc[j][i][2], a3 = acc[j][i][3];
        short4v ov;
        ov[0] = f2b(a0 * c0 - a1 * s0);
        ov[1] = f2b(a1 * c1 + a0 * s1);
        ov[2] = f2b(a2 * c2 - a3 * s2);
        ov[3] = f2b(a3 * c3 + a2 * s3);
        *reinterpret_cast<short4v*>(dst + ((size_t)bh * NSEQ + n) * DH + d0) = ov;
      }
    }
  }
}

// ---------------- Flash attention (r4-validated) ----------------
__global__ __launch_bounds__(256, 4) void attn_kernel(const bf16* __restrict__ Q, const bf16* __restrict__ K,
                                                      const bf16* __restrict__ Vt, bf16* __restrict__ AO) {
  int bh = blockIdx.x, qt = blockIdx.y;
  int tid = threadIdx.x;
  int wave = tid >> 6, lane = tid & 63;
  int l15 = lane & 15, quad = lane >> 4;
  int qf = wave & 1;   // q half: rows [qf*32, qf*32+32)
  int ks = wave >> 1;  // k slice: cols [ks*32, ks*32+32) of each 64-tile
  int m0 = qt * 64 + qf * 32;
  const bf16* Qb = Q + (size_t)bh * NSEQ * DH;
  const bf16* Kb = K + (size_t)bh * NSEQ * DH;
  const bf16* Vb = Vt + (size_t)bh * DH * NSEQ;

  __shared__ __align__(16) bf16 kbuf[2][64 * 72];
  __shared__ __align__(16) bf16 vbuf[2][64 * 72];

  // staging: 256 threads cover 512 short8 slots per tile (2 K + 2 V each)
  int r1 = tid >> 3, c1 = (tid & 7) * 8;
  int r1b = r1 + 32;

  // Q pre-scaled by 0.125 * log2(e) so p = exp2(s) directly
  const float QS = 0.18033688011112042f;
  short8 qa0 = ld8(Qb + (size_t)(m0 + l15) * DH + quad * 8);
  short8 qa1 = ld8(Qb + (size_t)(m0 + l15) * DH + 32 + quad * 8);
  short8 qb0 = ld8(Qb + (size_t)(m0 + 16 + l15) * DH + quad * 8);
  short8 qb1 = ld8(Qb + (size_t)(m0 + 16 + l15) * DH + 32 + quad * 8);
#pragma unroll
  for (int i = 0; i < 8; ++i) {
    qa0[i] = f2b(b2f(qa0[i]) * QS);
    qa1[i] = f2b(b2f(qa1[i]) * QS);
    qb0[i] = f2b(b2f(qb0[i]) * QS);
    qb1[i] = f2b(b2f(qb1[i]) * QS);
  }

  f32x4 z = {0.f, 0.f, 0.f, 0.f};
  f32x4 o[4] = {z, z, z, z};
  f32x4 o2[4] = {z, z, z, z};
  float l_run = 0.f, l_run2 = 0.f;

  // stage K/V tile 0
  *reinterpret_cast<short8*>(kbuf[0] + r1 * 72 + c1)  = ld8(Kb + (size_t)r1 * DH + c1);
  *reinterpret_cast<short8*>(kbuf[0] + r1b * 72 + c1) = ld8(Kb + (size_t)r1b * DH + c1);
  *reinterpret_cast<short8*>(vbuf[0] + r1 * 72 + c1)  = ld8(Vb + (size_t)r1 * NSEQ + c1);
  *reinterpret_cast<short8*>(vbuf[0] + r1b * 72 + c1) = ld8(Vb + (size_t)r1b * NSEQ + c1);
  __syncthreads();

  for (int it = 0; it < NSEQ / 64; ++it) {
    int cur = it & 1;
    bool more = (it + 1 < NSEQ / 64);

    // prefetch next K/V tile into registers (global)
    short8 kpA, kpB, vpA, vpB;
    if (more) {
      int kn = (it + 1) * 64;
      kpA = ld8(Kb + (size_t)(kn + r1) * DH + c1);
      kpB = ld8(Kb + (size_t)(kn + r1b) * DH + c1);
      vpA = ld8(Vb + (size_t)r1 * NSEQ + kn + c1);
      vpB = ld8(Vb + (size_t)r1b * NSEQ + kn + c1);
    }

    const bf16* kb = kbuf[cur];
    const bf16* vb = vbuf[cur];

    // QK^T for this wave's 32 k-rows x 32 q-rows
    f32x4 s[2], s2[2];
#pragma unroll
    for (int kt = 0; kt < 2; ++kt) {
      const bf16* kp = kb + (size_t)(ks * 32 + kt * 16 + l15) * 72 + quad * 8;
      short8 kf0 = lds8(kp);
      short8 kf1 = lds8(kp + 32);
      s[kt] = mfma_bf16(kf0, qa0, z);
      s[kt] = mfma_bf16(kf1, qa1, s[kt]);
      s2[kt] = mfma_bf16(kf0, qb0, z);
      s2[kt] = mfma_bf16(kf1, qb1, s2[kt]);
    }

    // exp2 + in-register P->B-frag redistribution (no LDS)
    unsigned int A0, B0, A1, B1, C0, D0, C1, D1;
    {
      float p00 = EXP2F(s[0][0]), p01 = EXP2F(s[0][1]), p02 = EXP2F(s[0][2]), p03 = EXP2F(s[0][3]);
      float p10 = EXP2F(s[1][0]), p11 = EXP2F(s[1][1]), p12 = EXP2F(s[1][2]), p13 = EXP2F(s[1][3]);
      l_run += ((p00 + p01) + (p02 + p03)) + ((p10 + p11) + (p12 + p13));
      asm("v_cvt_pk_bf16_f32 %0, %1, %2" : "=v"(A0) : "v"(p00), "v"(p01));
      asm("v_cvt_pk_bf16_f32 %0, %1, %2" : "=v"(B0) : "v"(p02), "v"(p03));
      asm("v_cvt_pk_bf16_f32 %0, %1, %2" : "=v"(A1) : "v"(p10), "v"(p11));
      asm("v_cvt_pk_bf16_f32 %0, %1, %2" : "=v"(B1) : "v"(p12), "v"(p13));
      float q00 = EXP2F(s2[0][0]), q01 = EXP2F(s2[0][1]), q02 = EXP2F(s2[0][2]), q03 = EXP2F(s2[0][3]);
      float q10 = EXP2F(s2[1][0]), q11 = EXP2F(s2[1][1]), q12 = EXP2F(s2[1][2]), q13 = EXP2F(s2[1][3]);
      l_run2 += ((q00 + q01) + (q02 + q03)) + ((q10 + q11) + (q12 + q13));
      asm("v_cvt_pk_bf16_f32 %0, %1, %2" : "=v"(C0) : "v"(q00), "v"(q01));
      asm("v_cvt_pk_bf16_f32 %0, %1, %2" : "=v"(D0) : "v"(q02), "v"(q03));
      asm("v_cvt_pk_bf16_f32 %0, %1, %2" : "=v"(C1) : "v"(q10), "v"(q11));
      asm("v_cvt_pk_bf16_f32 %0, %1, %2" : "=v"(D1) : "v"(q12), "v"(q13));
    }
    asm("v_permlane32_swap_b32 %0, %1" : "+v"(A0), "+v"(A1));
    asm("v_permlane16_swap_b32 %0, %1" : "+v"(A0), "+v"(A1));
    asm("v_permlane32_swap_b32 %0, %1" : "+v"(B0), "+v"(B1));
    asm("v_permlane16_swap_b32 %0, %1" : "+v"(B0), "+v"(B1));
    asm("v_permlane32_swap_b32 %0, %1" : "+v"(C0), "+v"(C1));
    asm("v_permlane16_swap_b32 %0, %1" : "+v"(C0), "+v"(C1));
    asm("v_permlane32_swap_b32 %0, %1" : "+v"(D0), "+v"(D1));
    asm("v_permlane16_swap_b32 %0, %1" : "+v"(D0), "+v"(D1));

    u32x4 wA; wA[0] = A0; wA[1] = B0; wA[2] = A1; wA[3] = B1;
    u32x4 wB; wB[0] = C0; wB[1] = D0; wB[2] = C1; wB[3] = D1;
    short8 pfA = *reinterpret_cast<short8*>(&wA);
    short8 pfB = *reinterpret_cast<short8*>(&wB);

    // PV for this wave's 32 k-cols (partial o over the k-slice)
#pragma unroll
    for (int t = 0; t < 4; ++t) {
      short8 vf = lds8(vb + (size_t)(t * 16 + l15) * 72 + ks * 32 + quad * 8);
      o[t] = mfma_bf16(vf, pfA, o[t]);
      o2[t] = mfma_bf16(vf, pfB, o2[t]);
    }

    if (more) {
      bf16* kn_ = kbuf[1 - cur];
      bf16* vn_ = vbuf[1 - cur];
      *reinterpret_cast<short8*>(kn_ + r1 * 72 + c1)  = kpA;
      *reinterpret_cast<short8*>(kn_ + r1b * 72 + c1) = kpB;
      *reinterpret_cast<short8*>(vn_ + r1 * 72 + c1)  = vpA;
      *reinterpret_cast<short8*>(vn_ + r1b * 72 + c1) = vpB;
    }
    __syncthreads();
  }

  // ---- cross-kslice combine via LDS scratch (kbuf is dead now) ----
  float* scr = (float*)kbuf;
  int slot = qf * 64 + lane;  // wave2 pairs wave0 (qf=0), wave3 pairs wave1
  if (ks == 1) {
    float* p = scr + slot * 36;
#pragma unroll
    for (int t = 0; t < 4; ++t) {
      *reinterpret_cast<f32x4*>(p + t * 4) = o[t];
      *reinterpret_cast<f32x4*>(p + 16 + t * 4) = o2[t];
    }
    p[32] = l_run;
    p[33] = l_run2;
  }
  __syncthreads();
  if (ks == 0) {
    float* p = scr + slot * 36;
#pragma unroll
    for (int t = 0; t < 4; ++t) {
      f32x4 pa = *reinterpret_cast<f32x4*>(p + t * 4);
      f32x4 pb2 = *reinterpret_cast<f32x4*>(p + 16 + t * 4);
#pragma unroll
      for (int r = 0; r < 4; ++r) {
        o[t][r] += pa[r];
        o2[t][r] += pb2[r];
      }
    }
    l_run += p[32];
    l_run2 += p[33];

    l_run += __shfl_xor(l_run, 16);
    l_run += __shfl_xor(l_run, 32);
    l_run2 += __shfl_xor(l_run2, 16);
    l_run2 += __shfl_xor(l_run2, 32);
    float inv = 1.f / l_run;
    float inv2 = 1.f / l_run2;
    int b = bh >> 2, h = bh & 3;
    bf16* orow = AO + ((size_t)b * NSEQ + (m0 + l15)) * CDIM + h * DH;
    bf16* orow2 = AO + ((size_t)b * NSEQ + (m0 + 16 + l15)) * CDIM + h * DH;
#pragma unroll
    for (int t = 0; t < 4; ++t) {
      short4v ov, ov2;
#pragma unroll
      for (int r = 0; r < 4; ++r) {
        ov[r] = f2b(o[t][r] * inv);
        ov2[r] = f2b(o2[t][r] * inv2);
      }
      *reinterpret_cast<short4v*>(orow + t * 16 + quad * 4) = ov;
      *reinterpret_cast<short4v*>(orow2 + t * 16 + quad * 4) = ov2;
    }
  }
}

// ---------------- Canonical 128-tile GEMM (r12-validated, used for FC1) ----------------
template <int KD, int EPI, int TI>
__global__ __launch_bounds__(256) void gemm128(const bf16* __restrict__ A, const bf16* __restrict__ Wm,
                                               const bf16* __restrict__ bias, const bf16* __restrict__ res,
                                               bf16* __restrict__ outp, int NC) {
  constexpr int KS = KD / 32;
  constexpr int AR = TI * 32;
  int tid = threadIdx.x;
  int wave = tid >> 6, lane = tid & 63;
  int l15 = lane & 15, quad = lane >> 4;
  int wm = (wave >> 1) * (TI * 16);
  int wn = (wave & 1) * 64;
  int m0 = blockIdx.x * AR;
  int n0 = blockIdx.y * 128;

  __shared__ __align__(16) bf16 abuf[2][AR * 40];
  __shared__ __align__(16) bf16 bbuf[2][128 * 40];

  int sr = tid >> 2, sc = (tid & 3) * 8;

  const bf16* ag[TI / 2];
#pragma unroll
  for (int u = 0; u < TI / 2; ++u) ag[u] = A + (size_t)(m0 + sr + u * 64) * KD + sc;
  const bf16* bg0 = Wm + (size_t)(n0 + sr) * KD + sc;
  const bf16* bg1 = Wm + (size_t)(n0 + 64 + sr) * KD + sc;

  f32x4 z = {0.f, 0.f, 0.f, 0.f};
  f32x4 acc[4][TI];
#pragma unroll
  for (int j = 0; j < 4; ++j)
#pragma unroll
    for (int i = 0; i < TI; ++i) acc[j][i] = z;

#pragma unroll
  for (int u = 0; u < TI / 2; ++u)
    *reinterpret_cast<short8*>(abuf[0] + (sr + u * 64) * 40 + sc) = ld8(ag[u]);
  *reinterpret_cast<short8*>(bbuf[0] + sr * 40 + sc) = ld8(bg0);
  *reinterpret_cast<short8*>(bbuf[0] + (64 + sr) * 40 + sc) = ld8(bg1);
  __syncthreads();

  for (int s = 0; s < KS; ++s) {
    int cur = s & 1;
    bool more = (s + 1 < KS);
    short8 anx[TI / 2], bnx0, bnx1;
    if (more) {
#pragma unroll
      for (int u = 0; u < TI / 2; ++u) anx[u] = ld8(ag[u] + (s + 1) * 32);
      bnx0 = ld8(bg0 + (s + 1) * 32);
      bnx1 = ld8(bg1 + (s + 1) * 32);
    }
    short8 af[TI], bf_[4];
#pragma unroll
    for (int i = 0; i < TI; ++i)
      af[i] = lds8(abuf[cur] + (size_t)(wm + i * 16 + l15) * 40 + quad * 8);
#pragma unroll
    for (int j = 0; j < 4; ++j)
      bf_[j] = lds8(bbuf[cur] + (size_t)(wn + j * 16 + l15) * 40 + quad * 8);
#pragma unroll
    for (int j = 0; j < 4; ++j)
#pragma unroll
      for (int i = 0; i < TI; ++i)
        acc[j][i] = mfma_bf16(bf_[j], af[i], acc[j][i]);
    if (more) {
#pragma unroll
      for (int u = 0; u < TI / 2; ++u)
        *reinterpret_cast<short8*>(abuf[1 - cur] + (sr + u * 64) * 40 + sc) = anx[u];
      *reinterpret_cast<short8*>(bbuf[1 - cur] + sr * 40 + sc) = bnx0;
      *reinterpret_cast<short8*>(bbuf[1 - cur] + (64 + sr) * 40 + sc) = bnx1;
    }
    __syncthreads();
  }

#pragma unroll
  for (int j = 0; j < 4; ++j) {
    int col0 = n0 + wn + j * 16 + quad * 4;
    float bb4[4];
    if (EPI != 0) {
      short4v bl = *reinterpret_cast<const short4v*>(bias + col0);
#pragma unroll
      for (int r = 0; r < 4; ++r) bb4[r] = b2f(bl[r]);
    }
#pragma unroll
    for (int i = 0; i < TI; ++i) {
      size_t idx = (size_t)(m0 + wm + i * 16 + l15) * NC + col0;
      short4v ov;
      if (EPI == 0) {
        short4v rl = *reinterpret_cast<const short4v*>(res + idx);
#pragma unroll
        for (int r = 0; r < 4; ++r) ov[r] = f2b(acc[j][i][r] + b2f(rl[r]));
      } else if (EPI == 1) {
#pragma unroll
        for (int r = 0; r < 4; ++r) {
          float hv = acc[j][i][r] + bb4[r];
          ov[r] = f2b(0.5f * hv * (1.f + erff(hv * 0.70710678118f)));
        }
      } else {
        short4v rl = *reinterpret_cast<const short4v*>(res + idx);
#pragma unroll
        for (int r = 0; r < 4; ++r) ov[r] = f2b(acc[j][i][r] + bb4[r] + b2f(rl[r]));
      }
      *reinterpret_cast<short4v*>(outp + idx) = ov;
    }
  }
}

// ---------------- GEMM (NC=256) with residual + FUSED LayerNorm epilogue ----------------
// Block = 32 rows x 256 cols (full rows -> LN feasible in-epilogue), 4 waves,
// wave w owns cols [w*64, w*64+64), all waves share rows. Same 288-block
// count and per-block MFMA volume as the old 64x128 tiling. LN: per-lane
// partials -> shfl_xor(16/32) quad reduce -> 1KB LDS cross-wave -> normalize.
// HASBIAS: add bias before residual. FINAL: write flag-dtype to void* out.
template <int KD, int HASBIAS, int FINAL>
__global__ __launch_bounds__(256) void gemm_ln(const bf16* __restrict__ A, const bf16* __restrict__ Wm,
                                               const bf16* __restrict__ bias, const bf16* __restrict__ res,
                                               const bf16* __restrict__ g, const bf16* __restrict__ bv,
                                               void* __restrict__ outp, const int* __restrict__ flag) {
  constexpr int KS = KD / 32;
  int tid = threadIdx.x;
  int wave = tid >> 6, lane = tid & 63;
  int l15 = lane & 15, quad = lane >> 4;
  int wn = wave * 64;
  int m0 = blockIdx.x * 32;
  int is32 = FINAL ? flag[0] : 0;

  __shared__ __align__(16) bf16 abuf[2][32 * 40];
  __shared__ __align__(16) bf16 bbuf[2][256 * 40];
  __shared__ float red[4][32][2];

  int sr = tid >> 2, sc = (tid & 3) * 8;      // B: rows sr+u*64, u=0..3
  bool doA = tid < 128;
  int ra = tid >> 2, ca = (tid & 3) * 8;      // A: rows 0..31 (tid<128)

  const bf16* ag = A + (size_t)(m0 + ra) * KD + ca;
  const bf16* bg[4];
#pragma unroll
  for (int u = 0; u < 4; ++u) bg[u] = Wm + (size_t)(sr + u * 64) * KD + sc;

  f32x4 z = {0.f, 0.f, 0.f, 0.f};
  f32x4 acc[4][2];
#pragma unroll
  for (int j = 0; j < 4; ++j)
#pragma unroll
    for (int i = 0; i < 2; ++i) acc[j][i] = z;

  if (doA) *reinterpret_cast<short8*>(abuf[0] + ra * 40 + ca) = ld8(ag);
#pragma unroll
  for (int u = 0; u < 4; ++u)
    *reinterpret_cast<short8*>(bbuf[0] + (sr + u * 64) * 40 + sc) = ld8(bg[u]);
  __syncthreads();

  for (int s = 0; s < KS; ++s) {
    int cur = s & 1;
    bool more = (s + 1 < KS);
    short8 anx, bnx[4];
    if (more) {
      if (doA) anx = ld8(ag + (s + 1) * 32);
#pragma unroll
      for (int u = 0; u < 4; ++u) bnx[u] = ld8(bg[u] + (s + 1) * 32);
    }
    short8 af[2], bf_[4];
#pragma unroll
    for (int i = 0; i < 2; ++i)
      af[i] = lds8(abuf[cur] + (size_t)(i * 16 + l15) * 40 + quad * 8);
#pragma unroll
    for (int j = 0; j < 4; ++j)
      bf_[j] = lds8(bbuf[cur] + (size_t)(wn + j * 16 + l15) * 40 + quad * 8);
#pragma unroll
    for (int j = 0; j < 4; ++j)
#pragma unroll
      for (int i = 0; i < 2; ++i)
        acc[j][i] = mfma_bf16(bf_[j], af[i], acc[j][i]);
    if (more) {
      if (doA) *reinterpret_cast<short8*>(abuf[1 - cur] + ra * 40 + ca) = anx;
#pragma unroll
      for (int u = 0; u < 4; ++u)
        *reinterpret_cast<short8*>(bbuf[1 - cur] + (sr + u * 64) * 40 + sc) = bnx[u];
    }
    __syncthreads();
  }

  // ---- epilogue: bias + residual, then fused LayerNorm over the full row ----
  float bb[4][4];
  if (HASBIAS) {
#pragma unroll
    for (int j = 0; j < 4; ++j) {
      short4v bl = *reinterpret_cast<const short4v*>(bias + wn + j * 16 + quad * 4);
#pragma unroll
      for (int r = 0; r < 4; ++r) bb[j][r] = b2f(bl[r]);
    }
  }
  float vals[2][4][4];
  float s0 = 0.f, q0 = 0.f, s1 = 0.f, q1 = 0.f;
#pragma unroll
  for (int i = 0; i < 2; ++i) {
    int row = m0 + i * 16 + l15;
#pragma unroll
    for (int j = 0; j < 4; ++j) {
      int col0 = wn + j * 16 + quad * 4;
      short4v rl = *reinterpret_cast<const short4v*>(res + (size_t)row * CDIM + col0);
#pragma unroll
      for (int r = 0; r < 4; ++r) {
        float v = acc[j][i][r] + (HASBIAS ? bb[j][r] : 0.f) + b2f(rl[r]);
        vals[i][j][r] = v;
        if (i == 0) { s0 += v; q0 += v * v; }
        else        { s1 += v; q1 += v * v; }
      }
    }
  }
  s0 += __shfl_xor(s0, 16); s0 += __shfl_xor(s0, 32);
  q0 += __shfl_xor(q0, 16); q0 += __shfl_xor(q0, 32);
  s1 += __shfl_xor(s1, 16); s1 += __shfl_xor(s1, 32);
  q1 += __shfl_xor(q1, 16); q1 += __shfl_xor(q1, 32);
  if (quad == 0) {
    red[wave][l15][0] = s0;      red[wave][l15][1] = q0;
    red[wave][16 + l15][0] = s1; red[wave][16 + l15][1] = q1;
  }
  __syncthreads();

#pragma unroll
  for (int i = 0; i < 2; ++i) {
    int rl_ = i * 16 + l15;
    float S = 0.f, Q = 0.f;
#pragma unroll
    for (int w = 0; w < 4; ++w) { S += red[w][rl_][0]; Q += red[w][rl_][1]; }
    float mu = S * (1.f / CDIM);
    float var = Q * (1.f / CDIM) - mu * mu;
    float rstd = rsqrtf(var + 1e-5f);
    int row = m0 + i * 16 + l15;
#pragma unroll
    for (int j = 0; j < 4; ++j) {
      int col0 = wn + j * 16 + quad * 4;
      short4v gl = *reinterpret_cast<const short4v*>(g + col0);
      short4v bl2 = *reinterpret_cast<const short4v*>(bv + col0);
      size_t idx = (size_t)row * CDIM + col0;
      if (FINAL && is32) {
        float4 ov;
        ov.x = (vals[i][j][0] - mu) * rstd * b2f(gl[0]) + b2f(bl2[0]);
        ov.y = (vals[i][j][1] - mu) * rstd * b2f(gl[1]) + b2f(bl2[1]);
        ov.z = (vals[i][j][2] - mu) * rstd * b2f(gl[2]) + b2f(bl2[2]);
        ov.w = (vals[i][j][3] - mu) * rstd * b2f(gl[3]) + b2f(bl2[3]);
        *reinterpret_cast<float4*>((float*)outp + idx) = ov;
      } else {
        short4v ov;
#pragma unroll
        for (int r = 0; r < 4; ++r)
          ov[r] = f2b((vals[i][j][r] - mu) * rstd * b2f(gl[r]) + b2f(bl2[r]));
        *reinterpret_cast<short4v*>((bf16*)outp + idx) = ov;
      }
    }
  }
}

extern "C" void kernel_launch(void* const* d_in, const int* in_sizes, int n_in,
                              void* d_out, int out_size, void* d_ws, size_t ws_size,
                              hipStream_t stream) {
  const int* Wp = (const int*)d_in[12];

  char* ws = (char*)d_ws;
  const size_t SZ = 4718592;  // 2304*4*256 bf16 bytes
  bf16* Qc  = (bf16*)(ws + 0 * SZ);
  bf16* Kc  = (bf16*)(ws + 1 * SZ);
  bf16* Vt  = (bf16*)(ws + 2 * SZ);
  bf16* AO  = (bf16*)(ws + 3 * SZ);
  bf16* F   = (bf16*)(ws + 4 * SZ);
  bf16* xc  = (bf16*)(ws + 6 * SZ);
  bf16* G   = (bf16*)(ws + 0);              // overlays Qc..AO (4*SZ exactly)
  bf16* Wqkvc  = (bf16*)(ws + 7 * SZ);
  bf16* Wprojc = (bf16*)(ws + 7 * SZ + 393216);
  bf16* W1c    = (bf16*)(ws + 7 * SZ + 524288);
  bf16* W2c    = (bf16*)(ws + 7 * SZ + 1048576);
  bf16* smallc = (bf16*)(ws + 7 * SZ + 1572864);
  bf16* g1c  = smallc + 0;
  bf16* b1c  = smallc + 256;
  bf16* g2c  = smallc + 512;
  bf16* b2c  = smallc + 768;
  bf16* bf1c = smallc + 1024;
  bf16* bf2c = smallc + 2048;
  int*  flagp = (int*)(ws + 7 * SZ + 1581568);

  detect_kernel<<<1, 256, 0, stream>>>(d_in[0], flagp);
  cvt_all_kernel<<<3073, 256, 0, stream>>>(d_in[0], d_in[1], d_in[2], d_in[7], d_in[9],
                                           d_in[3], d_in[4], d_in[5], d_in[6], d_in[8], d_in[10],
                                           xc, Wqkvc, Wprojc, W1c, W2c, smallc, flagp);

  qkv_kernel<<<dim3(36, 12), 256, 0, stream>>>(xc, Wqkvc, Qc, Kc, Vt, Wp);
  attn_kernel<<<dim3(16, 36), 256, 0, stream>>>(Qc, Kc, Vt, AO);
  // proj + residual + LN1 -> F (bf16)
  gemm_ln<256, 0, 0><<<288, 256, 0, stream>>>(AO, Wprojc, nullptr, xc, g1c, b1c, F, flagp);
  // FC1 + bias + GELU -> G
  gemm128<256, 1, 4><<<dim3(72, 8), 256, 0, stream>>>(F, W1c, bf1c, nullptr, G, 1024);
  // FC2 + bias + residual(F) + LN2 -> d_out (flag dtype)
  gemm_ln<1024, 1, 1><<<288, 256, 0, stream>>>(G, W2c, bf2c, F, g2c, b2c, d_out, flagp);
}